// Round 2
// baseline (1709.852 us; speedup 1.0000x reference)
//
#include <hip/hip_runtime.h>
#include <hip/hip_bf16.h>

// Performer causal attention, chunked-scan formulation. B=4 T=4096 H=12 E=64 M=266.
// ws budget ~164MB: phiq bf16 (107MB) + kv-prefix bf16 (63MB) + z-prefix f32 (2MB) + kmax.
// phi_k is recomputed on the fly everywhere (needs only global kmax).

constexpr int Bn = 4, Tn = 4096, Hn = 12, En = 64;
constexpr int Mn = 266, MPn = 272;       // M padded to 272 (zeros in pad)
constexpr int BHn = Bn * Hn;             // 48
constexpr int CHn = 128;                 // chunk length
constexpr int NCn = Tn / CHn;            // 32 chunks
constexpr int MKVn = 320;                // m-slots in kv buffer (5*64)

constexpr float DATA_NORM = 0.35355339059327379f;  // 64^-0.25
constexpr float SM_EPS = 1e-4f;
constexpr float N_EPS  = 1e-6f;
constexpr float RATIO  = 0.06131393152401153f;     // 266^-0.5

__device__ __forceinline__ void unpack8(const void* src, float* f) {
  uint4 r = *reinterpret_cast<const uint4*>(src);
  f[0] = __uint_as_float(r.x << 16);
  f[1] = __uint_as_float(r.x & 0xffff0000u);
  f[2] = __uint_as_float(r.y << 16);
  f[3] = __uint_as_float(r.y & 0xffff0000u);
  f[4] = __uint_as_float(r.z << 16);
  f[5] = __uint_as_float(r.z & 0xffff0000u);
  f[6] = __uint_as_float(r.w << 16);
  f[7] = __uint_as_float(r.w & 0xffff0000u);
}

__device__ __forceinline__ void unpack8v(uint4 r, float* f) {
  f[0] = __uint_as_float(r.x << 16);
  f[1] = __uint_as_float(r.x & 0xffff0000u);
  f[2] = __uint_as_float(r.y << 16);
  f[3] = __uint_as_float(r.y & 0xffff0000u);
  f[4] = __uint_as_float(r.z << 16);
  f[5] = __uint_as_float(r.z & 0xffff0000u);
  f[6] = __uint_as_float(r.w << 16);
  f[7] = __uint_as_float(r.w & 0xffff0000u);
}

__device__ __forceinline__ unsigned short f2bf(float f) {
  __hip_bfloat16 h = __float2bfloat16(f);
  return __builtin_bit_cast(unsigned short, h);
}
__device__ __forceinline__ float bf2f(unsigned short u) {
  return __uint_as_float(((unsigned)u) << 16);
}
__device__ __forceinline__ uint4 pack8(const float* f) {
  uint4 r;
  r.x = (unsigned)f2bf(f[0]) | ((unsigned)f2bf(f[1]) << 16);
  r.y = (unsigned)f2bf(f[2]) | ((unsigned)f2bf(f[3]) << 16);
  r.z = (unsigned)f2bf(f[4]) | ((unsigned)f2bf(f[5]) << 16);
  r.w = (unsigned)f2bf(f[6]) | ((unsigned)f2bf(f[7]) << 16);
  return r;
}

__device__ __forceinline__ void atomicMaxF(float* addr, float val) {
  if (val >= 0.f) atomicMax(reinterpret_cast<int*>(addr), __float_as_int(val));
  else atomicMin(reinterpret_cast<unsigned int*>(addr), __float_as_uint(val));
}

__global__ void init_kmax(float* kmax) {
  int t = threadIdx.x;
  if (t < BHn) kmax[t] = -__builtin_inff();
}

// MODE 0 = query (row max, write phi); MODE 1 = key (global max only).
template <int MODE>
__global__ __launch_bounds__(256) void feat_kernel(
    const float* __restrict__ x, const float* __restrict__ proj,
    __hip_bfloat16* __restrict__ phi, float* __restrict__ kmax) {
  constexpr int DDW = (MODE == 1) ? 4 : 276;
  __shared__ float Qt[64 * 68];      // [e][r] transposed, normalized
  __shared__ float P[64 * 68];       // [e][m_local]
  __shared__ float ddbuf[64 * DDW];  // [r][m]  (MODE 0 only)
  __shared__ float diag[64];
  __shared__ float pm[4 * 64];
  __shared__ float red[256];

  const int tid = threadIdx.x;
  const int blk = blockIdx.x;
  const int bh = blk / (Tn / 64);
  const int tt = blk % (Tn / 64);
  const int b = bh / Hn, h = bh % Hn;
  const int t0 = tt * 64;

  const float* xbase = x + (((size_t)b * Tn + t0) * Hn + h) * En;

  for (int l = 0; l < 4; ++l) {
    int idx = tid + l * 256;
    int r = idx >> 4, e4 = (idx & 15) * 4;
    float4 v = *reinterpret_cast<const float4*>(xbase + (size_t)r * (Hn * En) + e4);
    Qt[(e4 + 0) * 68 + r] = v.x * DATA_NORM;
    Qt[(e4 + 1) * 68 + r] = v.y * DATA_NORM;
    Qt[(e4 + 2) * 68 + r] = v.z * DATA_NORM;
    Qt[(e4 + 3) * 68 + r] = v.w * DATA_NORM;
  }
  __syncthreads();
  if (MODE == 0 && tid < 64) {
    float s = 0.f;
    for (int e = 0; e < 64; ++e) { float qv = Qt[e * 68 + tid]; s += qv * qv; }
    diag[tid] = 0.5f * s;
  }

  const int i = tid >> 4, j = tid & 15;
  float lmax = -__builtin_inff();

  for (int mt = 0; mt < 5; ++mt) {
    const int m0 = mt * 64;
    __syncthreads();
    for (int l = 0; l < 4; ++l) {
      int idx = tid + l * 256;
      int mr = idx >> 4, e4 = (idx & 15) * 4;
      int m = m0 + mr;
      float4 v = make_float4(0.f, 0.f, 0.f, 0.f);
      if (m < Mn) v = *reinterpret_cast<const float4*>(proj + (size_t)m * En + e4);
      P[(e4 + 0) * 68 + mr] = v.x;
      P[(e4 + 1) * 68 + mr] = v.y;
      P[(e4 + 2) * 68 + mr] = v.z;
      P[(e4 + 3) * 68 + mr] = v.w;
    }
    __syncthreads();
    float acc[4][4] = {};
#pragma unroll 4
    for (int e = 0; e < 64; ++e) {
      float4 qa = *reinterpret_cast<const float4*>(&Qt[e * 68 + i * 4]);
      float4 pb = *reinterpret_cast<const float4*>(&P[e * 68 + j * 4]);
      float qv[4] = {qa.x, qa.y, qa.z, qa.w};
      float pv[4] = {pb.x, pb.y, pb.z, pb.w};
#pragma unroll
      for (int a = 0; a < 4; ++a)
#pragma unroll
        for (int bb = 0; bb < 4; ++bb)
          acc[a][bb] = fmaf(qv[a], pv[bb], acc[a][bb]);
    }
    if (MODE == 1) {
#pragma unroll
      for (int a = 0; a < 4; ++a)
#pragma unroll
        for (int bb = 0; bb < 4; ++bb) {
          int m = m0 + j * 4 + bb;
          if (m < Mn) lmax = fmaxf(lmax, acc[a][bb]);
        }
    } else {
      if (m0 + j * 4 < MPn) {   // guard: last m-tile only covers 256..271
#pragma unroll
        for (int a = 0; a < 4; ++a) {
          float4 o = make_float4(acc[a][0], acc[a][1], acc[a][2], acc[a][3]);
          *reinterpret_cast<float4*>(&ddbuf[(size_t)(i * 4 + a) * DDW + m0 + j * 4]) = o;
        }
      }
    }
  }

  if (MODE == 1) {
    red[tid] = lmax;
    __syncthreads();
    for (int off = 128; off > 0; off >>= 1) {
      if (tid < off) red[tid] = fmaxf(red[tid], red[tid + off]);
      __syncthreads();
    }
    if (tid == 0) atomicMaxF(&kmax[bh], red[0]);
    return;
  }

  __syncthreads();
  const int r = tid & 63, seg = tid >> 6;
  float pmx = -__builtin_inff();
  for (int kk = 0; kk < 68; ++kk) {
    int m = seg * 68 + kk;
    if (m < Mn) pmx = fmaxf(pmx, ddbuf[(size_t)r * DDW + m]);
  }
  pm[seg * 64 + r] = pmx;
  __syncthreads();
  float mx = fmaxf(fmaxf(pm[r], pm[64 + r]), fmaxf(pm[128 + r], pm[192 + r]));
  const float dg = diag[r];
  __hip_bfloat16* orow = phi + ((size_t)bh * Tn + t0 + r) * MPn;
  for (int kk = 0; kk < 68; ++kk) {
    int m = seg * 68 + kk;
    float val = 0.f;
    if (m < Mn) val = RATIO * (__expf(ddbuf[(size_t)r * DDW + m] - dg - mx) + SM_EPS);
    orow[m] = __float2bfloat16(val);
  }
}

// Per (bh, chunk, m-slice): recompute phi_k, partial KV = phi_k^T @ V (bf16 out) + z partial.
__global__ __launch_bounds__(256) void stage_a(
    const float* __restrict__ k, const float* __restrict__ v,
    const float* __restrict__ proj, const float* __restrict__ kmax,
    __hip_bfloat16* __restrict__ kvp, float* __restrict__ zp) {
  __shared__ float arena[21504];   // 86KB
  __shared__ float diagk[128];
  float* phiK  = arena;            // [128][68]
  float* KnT   = arena + 8704;     // [64][132]
  float* projT = arena + 17152;    // [64][68]
  float* Vl    = arena + 8704;     // [128][68], overlaps KnT/projT (used after)

  const int tid = threadIdx.x;
  int blk = blockIdx.x;
  const int mt = blk % 5; blk /= 5;
  const int c = blk % NCn; const int bh = blk / NCn;
  const int b = bh / Hn, h = bh % Hn;
  const int t0 = c * CHn;
  const int m0 = mt * 64;
  const float kmx = kmax[bh];

  const float* kbase = k + (((size_t)b * Tn + t0) * Hn + h) * En;
  for (int l = 0; l < 8; ++l) {
    int idx = tid + l * 256;
    int r = idx >> 4, e4 = (idx & 15) * 4;
    float4 vv = *reinterpret_cast<const float4*>(kbase + (size_t)r * (Hn * En) + e4);
    KnT[(e4 + 0) * 132 + r] = vv.x * DATA_NORM;
    KnT[(e4 + 1) * 132 + r] = vv.y * DATA_NORM;
    KnT[(e4 + 2) * 132 + r] = vv.z * DATA_NORM;
    KnT[(e4 + 3) * 132 + r] = vv.w * DATA_NORM;
  }
  for (int l = 0; l < 4; ++l) {
    int idx = tid + l * 256;
    int mr = idx >> 4, e4 = (idx & 15) * 4;
    int m = m0 + mr;
    float4 vv = make_float4(0.f, 0.f, 0.f, 0.f);
    if (m < Mn) vv = *reinterpret_cast<const float4*>(proj + (size_t)m * En + e4);
    projT[(e4 + 0) * 68 + mr] = vv.x;
    projT[(e4 + 1) * 68 + mr] = vv.y;
    projT[(e4 + 2) * 68 + mr] = vv.z;
    projT[(e4 + 3) * 68 + mr] = vv.w;
  }
  __syncthreads();
  if (tid < 128) {
    float s = 0.f;
    for (int e = 0; e < 64; ++e) { float x = KnT[e * 132 + tid]; s += x * x; }
    diagk[tid] = 0.5f * s;
  }
  const int i = tid >> 4, j = tid & 15;
  float acc2[8][4] = {};
#pragma unroll 2
  for (int e = 0; e < 64; ++e) {
    float4 ka = *reinterpret_cast<const float4*>(&KnT[e * 132 + i * 8]);
    float4 kb = *reinterpret_cast<const float4*>(&KnT[e * 132 + i * 8 + 4]);
    float4 pv = *reinterpret_cast<const float4*>(&projT[e * 68 + j * 4]);
    float kr[8] = {ka.x, ka.y, ka.z, ka.w, kb.x, kb.y, kb.z, kb.w};
    float pr[4] = {pv.x, pv.y, pv.z, pv.w};
#pragma unroll
    for (int a = 0; a < 8; ++a)
#pragma unroll
      for (int bb = 0; bb < 4; ++bb)
        acc2[a][bb] = fmaf(kr[a], pr[bb], acc2[a][bb]);
  }
  __syncthreads();   // dd + diagk done; KnT/projT free

#pragma unroll
  for (int a = 0; a < 8; ++a) {
    int t = i * 8 + a;
    float dgk = diagk[t];
    float vals[4];
#pragma unroll
    for (int bb = 0; bb < 4; ++bb) {
      int m = m0 + j * 4 + bb;
      vals[bb] = (m < Mn) ? RATIO * (__expf(acc2[a][bb] - dgk - kmx) + SM_EPS) : 0.f;
    }
    *reinterpret_cast<float4*>(&phiK[t * 68 + j * 4]) =
        make_float4(vals[0], vals[1], vals[2], vals[3]);
  }
  const float* vbase = v + (((size_t)b * Tn + t0) * Hn + h) * En;
  for (int l = 0; l < 8; ++l) {
    int idx = tid + l * 256;
    int r = idx >> 4, d4 = (idx & 15) * 4;
    *reinterpret_cast<float4*>(&Vl[r * 68 + d4]) =
        *reinterpret_cast<const float4*>(vbase + (size_t)r * (Hn * En) + d4);
  }
  __syncthreads();

  float acc[4][4] = {};
#pragma unroll 4
  for (int t = 0; t < CHn; ++t) {
    float4 pk = *reinterpret_cast<const float4*>(&phiK[t * 68 + i * 4]);
    float4 vv = *reinterpret_cast<const float4*>(&Vl[t * 68 + j * 4]);
    float pa[4] = {pk.x, pk.y, pk.z, pk.w};
    float vb[4] = {vv.x, vv.y, vv.z, vv.w};
#pragma unroll
    for (int a = 0; a < 4; ++a)
#pragma unroll
      for (int bb = 0; bb < 4; ++bb)
        acc[a][bb] = fmaf(pa[a], vb[bb], acc[a][bb]);
  }
  __hip_bfloat16* kvout = kvp + (((size_t)bh * NCn + c) * MKVn + m0) * En;
#pragma unroll
  for (int a = 0; a < 4; ++a) {
    ushort4 o;
    o.x = f2bf(acc[a][0]); o.y = f2bf(acc[a][1]);
    o.z = f2bf(acc[a][2]); o.w = f2bf(acc[a][3]);
    *reinterpret_cast<ushort4*>(kvout + (i * 4 + a) * En + j * 4) = o;
  }
  if (tid < 64) {   // z partial: column sums of phiK
    float s = 0.f;
    for (int t = 0; t < CHn; ++t) s += phiK[t * 68 + tid];
    zp[((size_t)bh * NCn + c) * MKVn + m0 + tid] = s;
  }
}

// In-place exclusive prefix over chunks. Block per (bh, m-slice); f32 register accum.
__global__ __launch_bounds__(256) void scan_kernel(
    __hip_bfloat16* __restrict__ kv, float* __restrict__ zp) {
  const int tid = threadIdx.x;
  const int mt = blockIdx.x % 5, bh = blockIdx.x / 5;
  float acc[16];
#pragma unroll
  for (int q = 0; q < 16; ++q) acc[q] = 0.f;
  float zacc = 0.f;
  for (int c = 0; c < NCn; ++c) {
    size_t base = (((size_t)bh * NCn + c) * MKVn + mt * 64) * En + (size_t)tid * 16;
    uint4 r0 = *reinterpret_cast<const uint4*>(kv + base);
    uint4 r1 = *reinterpret_cast<const uint4*>(kv + base + 8);
    float in[16];
    unpack8v(r0, in);
    unpack8v(r1, in + 8);
    *reinterpret_cast<uint4*>(kv + base)     = pack8(acc);
    *reinterpret_cast<uint4*>(kv + base + 8) = pack8(acc + 8);
#pragma unroll
    for (int q = 0; q < 16; ++q) acc[q] += in[q];
    if (tid < 64) {
      size_t zb = ((size_t)bh * NCn + c) * MKVn + mt * 64 + tid;
      float t = zp[zb]; zp[zb] = zacc; zacc += t;
    }
  }
}

// Per chunk: recompute phi_k; A = mask(Qc Kc^T); out = A@Vc + Qc@S_prev;
// den = rowsum(A) + q.z_prev + eps.
__global__ __launch_bounds__(256) void stage_c(
    const float* __restrict__ k_in, const float* __restrict__ v,
    const float* __restrict__ proj, const float* __restrict__ kmax,
    const __hip_bfloat16* __restrict__ phiq, const __hip_bfloat16* __restrict__ kvpre,
    const float* __restrict__ zpre, float* __restrict__ out) {
  __shared__ float A[128 * 132];     // 67.6KB
  __shared__ float arena[19200];     // 76.8KB
  __shared__ float diagk[128];
  __shared__ float zl[MPn];
  __shared__ float den[128];
  float* Qt    = arena;              // [32][132]  phase 1
  float* Kt    = arena + 4224;       // [32][132]  phase 1
  float* KnT   = arena + 8448;       // [64][132]  phase 1
  float* projT = arena + 16896;      // [64][36]   phase 1
  float* Vl    = arena;              // [128][68]  phase 2a
  float* Qt2   = arena;              // [32][132]  phase 2b
  float* St    = arena + 4224;       // [32][68]   phase 2b

  const int tid = threadIdx.x;
  const int blk = blockIdx.x;
  const int c = blk % NCn, bh = blk / NCn;
  const int b = bh / Hn, h = bh % Hn;
  const int t0 = c * CHn;
  const int i = tid >> 4, j = tid & 15;
  const float kmx = kmax[bh];

  for (int m = tid; m < MPn; m += 256)
    zl[m] = zpre[((size_t)bh * NCn + c) * MKVn + m];

  const float* kbase = k_in + (((size_t)b * Tn + t0) * Hn + h) * En;
  for (int l = 0; l < 8; ++l) {
    int idx = tid + l * 256;
    int r = idx >> 4, e4 = (idx & 15) * 4;
    float4 vv = *reinterpret_cast<const float4*>(kbase + (size_t)r * (Hn * En) + e4);
    KnT[(e4 + 0) * 132 + r] = vv.x * DATA_NORM;
    KnT[(e4 + 1) * 132 + r] = vv.y * DATA_NORM;
    KnT[(e4 + 2) * 132 + r] = vv.z * DATA_NORM;
    KnT[(e4 + 3) * 132 + r] = vv.w * DATA_NORM;
  }
  __syncthreads();
  if (tid < 128) {
    float s = 0.f;
    for (int e = 0; e < 64; ++e) { float x = KnT[e * 132 + tid]; s += x * x; }
    diagk[tid] = 0.5f * s;
  }

  // ---- phase 1: A = Q K^T over m tiles (phi_k recomputed per tile) ----
  float acc1[8][8] = {};
  const bool skip1 = (i < j);
  for (int m0 = 0; m0 < MPn; m0 += 32) {
    const int mcnt = (MPn - m0 < 32) ? (MPn - m0) : 32;
    __syncthreads();
    const int ng = 128 * (mcnt >> 3);
    for (int idx = tid; idx < ng; idx += 256) {
      int t = idx & 127, mg = (idx >> 7) * 8;
      float f[8];
      unpack8(phiq + ((size_t)bh * Tn + t0 + t) * MPn + m0 + mg, f);
#pragma unroll
      for (int kk = 0; kk < 8; ++kk) Qt[(mg + kk) * 132 + t] = f[kk];
    }
    for (int l = 0; l < 2; ++l) {
      int idx = tid + l * 256;
      int ml = idx >> 4, e4 = (idx & 15) * 4;
      int m = m0 + ml;
      float4 vv = make_float4(0.f, 0.f, 0.f, 0.f);
      if (m < Mn) vv = *reinterpret_cast<const float4*>(proj + (size_t)m * En + e4);
      projT[(e4 + 0) * 36 + ml] = vv.x;
      projT[(e4 + 1) * 36 + ml] = vv.y;
      projT[(e4 + 2) * 36 + ml] = vv.z;
      projT[(e4 + 3) * 36 + ml] = vv.w;
    }
    __syncthreads();
    {
      float acc2[8][2] = {};
#pragma unroll 2
      for (int e = 0; e < 64; ++e) {
        float4 ka = *reinterpret_cast<const float4*>(&KnT[e * 132 + i * 8]);
        float4 kb = *reinterpret_cast<const float4*>(&KnT[e * 132 + i * 8 + 4]);
        float p0 = projT[e * 36 + j * 2], p1 = projT[e * 36 + j * 2 + 1];
        float kr[8] = {ka.x, ka.y, ka.z, ka.w, kb.x, kb.y, kb.z, kb.w};
#pragma unroll
        for (int a = 0; a < 8; ++a) {
          acc2[a][0] = fmaf(kr[a], p0, acc2[a][0]);
          acc2[a][1] = fmaf(kr[a], p1, acc2[a][1]);
        }
      }
#pragma unroll
      for (int ml = 0; ml < 2; ++ml) {
        int m = m0 + j * 2 + ml;
#pragma unroll
        for (int a = 0; a < 8; ++a) {
          int t = i * 8 + a;
          float val = (m < Mn)
              ? RATIO * (__expf(acc2[a][ml] - diagk[t] - kmx) + SM_EPS) : 0.f;
          Kt[(j * 2 + ml) * 132 + t] = val;
        }
      }
    }
    __syncthreads();
    if (!skip1) {
      for (int mm = 0; mm < mcnt; ++mm) {
        float4 qa = *reinterpret_cast<const float4*>(&Qt[mm * 132 + i * 8]);
        float4 qb = *reinterpret_cast<const float4*>(&Qt[mm * 132 + i * 8 + 4]);
        float4 ka = *reinterpret_cast<const float4*>(&Kt[mm * 132 + j * 8]);
        float4 kb = *reinterpret_cast<const float4*>(&Kt[mm * 132 + j * 8 + 4]);
        float qr[8] = {qa.x, qa.y, qa.z, qa.w, qb.x, qb.y, qb.z, qb.w};
        float kr[8] = {ka.x, ka.y, ka.z, ka.w, kb.x, kb.y, kb.z, kb.w};
#pragma unroll
        for (int a = 0; a < 8; ++a)
#pragma unroll
          for (int bb = 0; bb < 8; ++bb)
            acc1[a][bb] = fmaf(qr[a], kr[bb], acc1[a][bb]);
      }
    }
  }
  __syncthreads();
  if (i >= j) {
#pragma unroll
    for (int a = 0; a < 8; ++a) {
      int t = i * 8 + a;
      float vals[8];
#pragma unroll
      for (int bb = 0; bb < 8; ++bb) {
        int s = j * 8 + bb;
        vals[bb] = (i > j || s <= t) ? acc1[a][bb] : 0.f;
      }
      *reinterpret_cast<float4*>(&A[t * 132 + j * 8]) =
          make_float4(vals[0], vals[1], vals[2], vals[3]);
      *reinterpret_cast<float4*>(&A[t * 132 + j * 8 + 4]) =
          make_float4(vals[4], vals[5], vals[6], vals[7]);
    }
  }
  __syncthreads();

  // ---- phase 2a: out += mask(A) @ V; rowsum(A) ----
  for (int l = 0; l < 8; ++l) {
    int idx = tid + l * 256;
    int t = idx >> 4, d4 = (idx & 15) * 4;
    *reinterpret_cast<float4*>(&Vl[t * 68 + d4]) =
        *reinterpret_cast<const float4*>(v + (((size_t)b * Tn + t0 + t) * Hn + h) * En + d4);
  }
  __syncthreads();

  float oacc[8][4] = {};
  float rs[8] = {};
  float qz[8] = {};
  for (int s4 = 0; s4 < (i + 1) * 2; ++s4) {
    const int s = s4 * 4;
    float4 v0 = *reinterpret_cast<const float4*>(&Vl[(s + 0) * 68 + j * 4]);
    float4 v1 = *reinterpret_cast<const float4*>(&Vl[(s + 1) * 68 + j * 4]);
    float4 v2 = *reinterpret_cast<const float4*>(&Vl[(s + 2) * 68 + j * 4]);
    float4 v3 = *reinterpret_cast<const float4*>(&Vl[(s + 3) * 68 + j * 4]);
    float vv[4][4] = {{v0.x, v0.y, v0.z, v0.w},
                      {v1.x, v1.y, v1.z, v1.w},
                      {v2.x, v2.y, v2.z, v2.w},
                      {v3.x, v3.y, v3.z, v3.w}};
#pragma unroll
    for (int a = 0; a < 8; ++a) {
      float4 av = *reinterpret_cast<const float4*>(&A[(i * 8 + a) * 132 + s]);
      float am[4] = {av.x, av.y, av.z, av.w};
#pragma unroll
      for (int ss = 0; ss < 4; ++ss) {
        rs[a] += am[ss];
#pragma unroll
        for (int bb = 0; bb < 4; ++bb)
          oacc[a][bb] = fmaf(am[ss], vv[ss][bb], oacc[a][bb]);
      }
    }
  }

  // ---- phase 2b: out += Q @ S_prev; qz = q . z_prev ----
  for (int m0 = 0; m0 < MPn; m0 += 32) {
    const int mcnt = (MPn - m0 < 32) ? (MPn - m0) : 32;
    __syncthreads();
    const int ng = 128 * (mcnt >> 3);
    for (int idx = tid; idx < ng; idx += 256) {
      int t = idx & 127, mg = (idx >> 7) * 8;
      float f[8];
      unpack8(phiq + ((size_t)bh * Tn + t0 + t) * MPn + m0 + mg, f);
#pragma unroll
      for (int kk = 0; kk < 8; ++kk) Qt2[(mg + kk) * 132 + t] = f[kk];
    }
    for (int l = 0; l < 2; ++l) {
      int idx = tid + l * 256;
      int mr = idx >> 4, d4 = (idx & 15) * 4;
      if (mr < mcnt) {
        ushort4 u = *reinterpret_cast<const ushort4*>(
            kvpre + (((size_t)bh * NCn + c) * MKVn + m0 + mr) * En + d4);
        St[mr * 68 + d4 + 0] = bf2f(u.x);
        St[mr * 68 + d4 + 1] = bf2f(u.y);
        St[mr * 68 + d4 + 2] = bf2f(u.z);
        St[mr * 68 + d4 + 3] = bf2f(u.w);
      }
    }
    __syncthreads();
    for (int mm = 0; mm < mcnt; ++mm) {
      float4 qa = *reinterpret_cast<const float4*>(&Qt2[mm * 132 + i * 8]);
      float4 qb = *reinterpret_cast<const float4*>(&Qt2[mm * 132 + i * 8 + 4]);
      float4 sv = *reinterpret_cast<const float4*>(&St[mm * 68 + j * 4]);
      float z = zl[m0 + mm];
      float qr[8] = {qa.x, qa.y, qa.z, qa.w, qb.x, qb.y, qb.z, qb.w};
      float svv[4] = {sv.x, sv.y, sv.z, sv.w};
#pragma unroll
      for (int a = 0; a < 8; ++a) {
        qz[a] = fmaf(qr[a], z, qz[a]);
#pragma unroll
        for (int bb = 0; bb < 4; ++bb)
          oacc[a][bb] = fmaf(qr[a], svv[bb], oacc[a][bb]);
      }
    }
  }

  if (j == 0) {
#pragma unroll
    for (int a = 0; a < 8; ++a) den[i * 8 + a] = rs[a] + qz[a] + N_EPS;
  }
  __syncthreads();
#pragma unroll
  for (int a = 0; a < 8; ++a) {
    int t = i * 8 + a;
    float inv = 1.f / den[t];
    float4 o = make_float4(oacc[a][0] * inv, oacc[a][1] * inv,
                           oacc[a][2] * inv, oacc[a][3] * inv);
    *reinterpret_cast<float4*>(out + (((size_t)b * Tn + t0 + t) * Hn + h) * En + j * 4) = o;
  }
}

extern "C" void kernel_launch(void* const* d_in, const int* in_sizes, int n_in,
                              void* d_out, int out_size, void* d_ws, size_t ws_size,
                              hipStream_t stream) {
  const float* q = (const float*)d_in[0];
  const float* k = (const float*)d_in[1];
  const float* v = (const float*)d_in[2];
  const float* proj = (const float*)d_in[3];
  float* out = (float*)d_out;

  char* ws = (char*)d_ws;
  const size_t phi_bytes = (size_t)BHn * Tn * MPn * sizeof(__hip_bfloat16);      // 106.95 MB
  const size_t kv_bytes  = (size_t)BHn * NCn * MKVn * En * sizeof(__hip_bfloat16); // 62.9 MB
  const size_t z_bytes   = (size_t)BHn * NCn * MKVn * sizeof(float);             // 1.97 MB
  __hip_bfloat16* phiq = (__hip_bfloat16*)ws;
  __hip_bfloat16* kvp  = (__hip_bfloat16*)(ws + phi_bytes);
  float* zp   = (float*)(ws + phi_bytes + kv_bytes);
  float* kmax = (float*)(ws + phi_bytes + kv_bytes + z_bytes);

  init_kmax<<<1, 64, 0, stream>>>(kmax);
  feat_kernel<1><<<BHn * (Tn / 64), 256, 0, stream>>>(k, proj, nullptr, kmax);
  feat_kernel<0><<<BHn * (Tn / 64), 256, 0, stream>>>(q, proj, phiq, kmax);
  stage_a<<<BHn * NCn * 5, 256, 0, stream>>>(k, v, proj, kmax, kvp, zp);
  scan_kernel<<<BHn * 5, 256, 0, stream>>>(kvp, zp);
  stage_c<<<BHn * NCn, 256, 0, stream>>>(k, v, proj, kmax, phiq, kvp, zp, out);
}

// Round 3
// 417.566 us; speedup vs baseline: 4.0948x; 4.0948x over previous
//
#include <hip/hip_runtime.h>
#include <hip/hip_bf16.h>

// Performer causal attention, chunked scan, MFMA bf16 everywhere.
// B=4 T=4096 H=12 E=64 M=266 (padded 288). mfma_f32_16x16x32_bf16.

typedef unsigned short u16;
typedef __attribute__((ext_vector_type(8))) short bf16x8;   // 8 bf16 = 4 VGPR
typedef __attribute__((ext_vector_type(4))) float f32x4;

constexpr int Tn = 4096, Hn = 12;
constexpr int MP = 288;       // padded feature dim
constexpr int Mn = 266;
constexpr int CH = 128;       // chunk length
constexpr int NC = 32;        // chunks
constexpr int BH = 48;

constexpr float DATA_NORM = 0.35355339059327379f;  // 64^-0.25
constexpr float SM_EPS = 1e-4f;
constexpr float N_EPS  = 1e-6f;
constexpr float RATIO  = 0.06131393152401153f;     // 266^-0.5

// causal tile list (tt, tt') with tt' <= tt, 8x8 tiles of 16
__constant__ int cTT[36] = {0,1,1,2,2,2,3,3,3,3,4,4,4,4,4,5,5,5,5,5,5,6,6,6,6,6,6,6,7,7,7,7,7,7,7,7};
__constant__ int cTP[36] = {0,0,1,0,1,2,0,1,2,3,0,1,2,3,4,0,1,2,3,4,5,0,1,2,3,4,5,6,0,1,2,3,4,5,6,7};

__device__ __forceinline__ u16 f2bf(float f) {
  __hip_bfloat16 h = __float2bfloat16(f);
  return __builtin_bit_cast(u16, h);
}
__device__ __forceinline__ float bf2f(u16 u) {
  return __uint_as_float(((unsigned)u) << 16);
}
__device__ __forceinline__ bf16x8 ldb(const u16* p) {
  return *reinterpret_cast<const bf16x8*>(p);
}
__device__ __forceinline__ f32x4 mfma16(bf16x8 a, bf16x8 b, f32x4 c) {
  return __builtin_amdgcn_mfma_f32_16x16x32_bf16(a, b, c, 0, 0, 0);
}
__device__ __forceinline__ void atomicMaxF(float* addr, float val) {
  if (val >= 0.f) atomicMax(reinterpret_cast<int*>(addr), __float_as_int(val));
  else atomicMin(reinterpret_cast<unsigned int*>(addr), __float_as_uint(val));
}

// ---------------- prep: projbf [288][64] bf16 zero-padded; kmax init ----------------
__global__ void prep(const float* __restrict__ proj, u16* __restrict__ projbf,
                     float* __restrict__ kmax) {
  int idx = blockIdx.x * 256 + threadIdx.x;
  if (idx < MP * 64) {
    int m = idx >> 6, e = idx & 63;
    float v = (m < Mn) ? proj[m * 64 + e] : 0.f;
    projbf[idx] = f2bf(v);
  }
  if (blockIdx.x == 0 && threadIdx.x < BH) kmax[threadIdx.x] = -3.0e38f;
}

// ---------------- feat_q: phi_q = ratio*(exp(dd - diag - rowmax) + eps) ----------------
__global__ __launch_bounds__(256) void feat_q(
    const float* __restrict__ q, const u16* __restrict__ projbf,
    u16* __restrict__ phiq) {
  __shared__ __align__(16) u16 xt[64 * 72];
  __shared__ float diag[64];
  const int tid = threadIdx.x;
  const int bh = blockIdx.x >> 6, tb = blockIdx.x & 63;
  const int b = bh / Hn, h = bh % Hn;
  const int t0 = tb * 64;
  {
    const int t = tid >> 2, e0 = (tid & 3) * 16;
    const float* row = q + (((size_t)b * Tn + t0 + t) * Hn + h) * 64 + e0;
    float ss = 0.f;
#pragma unroll
    for (int q4 = 0; q4 < 4; ++q4) {
      float4 vv = *reinterpret_cast<const float4*>(row + q4 * 4);
      float x0 = vv.x * DATA_NORM, x1 = vv.y * DATA_NORM;
      float x2 = vv.z * DATA_NORM, x3 = vv.w * DATA_NORM;
      ss += x0 * x0 + x1 * x1 + x2 * x2 + x3 * x3;
      ushort4 uu = make_ushort4(f2bf(x0), f2bf(x1), f2bf(x2), f2bf(x3));
      *reinterpret_cast<ushort4*>(&xt[t * 72 + e0 + q4 * 4]) = uu;
    }
    ss += __shfl_xor(ss, 1);
    ss += __shfl_xor(ss, 2);
    if ((tid & 3) == 0) diag[t] = 0.5f * ss;
  }
  __syncthreads();
  const int lane = tid & 63, wv = tid >> 6;
  const int lj = lane & 15, lg = lane >> 4;
  bf16x8 a0 = ldb(&xt[(wv * 16 + lj) * 72 + lg * 8]);
  bf16x8 a1 = ldb(&xt[(wv * 16 + lj) * 72 + 32 + lg * 8]);
  f32x4 acc[17];
#pragma unroll
  for (int mt = 0; mt < 17; ++mt) {
    const u16* br = &projbf[(mt * 16 + lj) * 64 + lg * 8];
    f32x4 z = {0.f, 0.f, 0.f, 0.f};
    z = mfma16(a0, ldb(br), z);
    z = mfma16(a1, ldb(br + 32), z);
    acc[mt] = z;
  }
  float rmax[4] = {-3e38f, -3e38f, -3e38f, -3e38f};
#pragma unroll
  for (int mt = 0; mt < 17; ++mt) {
    int m = mt * 16 + lj;
    if (m < Mn) {
#pragma unroll
      for (int r = 0; r < 4; ++r) rmax[r] = fmaxf(rmax[r], acc[mt][r]);
    }
  }
#pragma unroll
  for (int r = 0; r < 4; ++r) {
    rmax[r] = fmaxf(rmax[r], __shfl_xor(rmax[r], 1));
    rmax[r] = fmaxf(rmax[r], __shfl_xor(rmax[r], 2));
    rmax[r] = fmaxf(rmax[r], __shfl_xor(rmax[r], 4));
    rmax[r] = fmaxf(rmax[r], __shfl_xor(rmax[r], 8));
  }
  float dg[4];
#pragma unroll
  for (int r = 0; r < 4; ++r) dg[r] = diag[wv * 16 + lg * 4 + r];
  u16* ob = phiq + ((size_t)bh * Tn + t0 + wv * 16) * MP;
#pragma unroll
  for (int mt = 0; mt < 17; ++mt) {
    int m = mt * 16 + lj;
#pragma unroll
    for (int r = 0; r < 4; ++r) {
      float val = 0.f;
      if (m < Mn)
        val = RATIO * (__expf(acc[mt][r] - dg[r] - rmax[r]) + SM_EPS);
      ob[(size_t)(lg * 4 + r) * MP + m] = f2bf(val);
    }
  }
#pragma unroll
  for (int r = 0; r < 4; ++r)   // m-tile 17 = all pad -> zeros
    ob[(size_t)(lg * 4 + r) * MP + 272 + lj] = 0;
}

// ---------------- feat_k: global max of dd; emit kn (bf16 x~) + diagk ----------------
__global__ __launch_bounds__(256) void feat_k(
    const float* __restrict__ k, const u16* __restrict__ projbf,
    u16* __restrict__ kn, float* __restrict__ diagk, float* __restrict__ kmax) {
  __shared__ __align__(16) u16 xt[64 * 72];
  __shared__ float wred[4];
  const int tid = threadIdx.x;
  const int bh = blockIdx.x >> 6, tb = blockIdx.x & 63;
  const int b = bh / Hn, h = bh % Hn;
  const int t0 = tb * 64;
  {
    const int t = tid >> 2, e0 = (tid & 3) * 16;
    const float* row = k + (((size_t)b * Tn + t0 + t) * Hn + h) * 64 + e0;
    u16* knr = kn + ((size_t)bh * Tn + t0 + t) * 64 + e0;
    float ss = 0.f;
#pragma unroll
    for (int q4 = 0; q4 < 4; ++q4) {
      float4 vv = *reinterpret_cast<const float4*>(row + q4 * 4);
      float x0 = vv.x * DATA_NORM, x1 = vv.y * DATA_NORM;
      float x2 = vv.z * DATA_NORM, x3 = vv.w * DATA_NORM;
      ss += x0 * x0 + x1 * x1 + x2 * x2 + x3 * x3;
      ushort4 uu = make_ushort4(f2bf(x0), f2bf(x1), f2bf(x2), f2bf(x3));
      *reinterpret_cast<ushort4*>(&xt[t * 72 + e0 + q4 * 4]) = uu;
      *reinterpret_cast<ushort4*>(knr + q4 * 4) = uu;
    }
    ss += __shfl_xor(ss, 1);
    ss += __shfl_xor(ss, 2);
    if ((tid & 3) == 0) diagk[(size_t)bh * Tn + t0 + t] = 0.5f * ss;
  }
  __syncthreads();
  const int lane = tid & 63, wv = tid >> 6;
  const int lj = lane & 15, lg = lane >> 4;
  bf16x8 a0 = ldb(&xt[(wv * 16 + lj) * 72 + lg * 8]);
  bf16x8 a1 = ldb(&xt[(wv * 16 + lj) * 72 + 32 + lg * 8]);
  float mx = -3e38f;
#pragma unroll
  for (int mt = 0; mt < 17; ++mt) {
    const u16* br = &projbf[(mt * 16 + lj) * 64 + lg * 8];
    f32x4 z = {0.f, 0.f, 0.f, 0.f};
    z = mfma16(a0, ldb(br), z);
    z = mfma16(a1, ldb(br + 32), z);
    int m = mt * 16 + lj;
    if (m < Mn)
      mx = fmaxf(mx, fmaxf(fmaxf(z[0], z[1]), fmaxf(z[2], z[3])));
  }
  mx = fmaxf(mx, __shfl_xor(mx, 1));
  mx = fmaxf(mx, __shfl_xor(mx, 2));
  mx = fmaxf(mx, __shfl_xor(mx, 4));
  mx = fmaxf(mx, __shfl_xor(mx, 8));
  mx = fmaxf(mx, __shfl_xor(mx, 16));
  mx = fmaxf(mx, __shfl_xor(mx, 32));
  if (lane == 0) wred[wv] = mx;
  __syncthreads();
  if (tid == 0)
    atomicMaxF(&kmax[bh], fmaxf(fmaxf(wred[0], wred[1]), fmaxf(wred[2], wred[3])));
}

// ---------------- stage_a: KV^T partial = V^T @ phi_k per chunk + z partial ----------------
__global__ __launch_bounds__(512) void stage_a(
    const float* __restrict__ v, const u16* __restrict__ kn,
    const u16* __restrict__ projbf, const float* __restrict__ diagk,
    const float* __restrict__ kmax, u16* __restrict__ kvT,
    float* __restrict__ zp) {
  __shared__ __align__(16) u16 knl[128 * 72];     // 18,432
  __shared__ __align__(16) u16 Vt[64 * 136];      // 17,408  (V^T [d][t])
  __shared__ __align__(16) u16 strip[288 * 40];   // 23,040  (phi_k^T [m][t-strip 32])
  __shared__ float dkl[128];
  const int tid = threadIdx.x, lane = tid & 63, wv = tid >> 6;
  const int lj = lane & 15, lg = lane >> 4;
  const int c = blockIdx.x & 31, bh = blockIdx.x >> 5;
  const int b = bh / Hn, h = bh % Hn;
  const int t0 = c * CH;
  const float kmx = kmax[bh];

#pragma unroll
  for (int l = 0; l < 2; ++l) {   // kn tile -> LDS
    int idx = tid + l * 512;
    int t = idx >> 3, e8 = (idx & 7) * 8;
    *reinterpret_cast<uint4*>(&knl[t * 72 + e8]) =
        *reinterpret_cast<const uint4*>(&kn[((size_t)bh * Tn + t0 + t) * 64 + e8]);
  }
#pragma unroll
  for (int l = 0; l < 4; ++l) {   // V -> V^T LDS bf16
    int idx = tid + l * 512;
    int t = idx >> 4, d4 = (idx & 15) * 4;
    float4 vv = *reinterpret_cast<const float4*>(
        &v[(((size_t)b * Tn + t0 + t) * Hn + h) * 64 + d4]);
    Vt[(d4 + 0) * 136 + t] = f2bf(vv.x);
    Vt[(d4 + 1) * 136 + t] = f2bf(vv.y);
    Vt[(d4 + 2) * 136 + t] = f2bf(vv.z);
    Vt[(d4 + 3) * 136 + t] = f2bf(vv.w);
  }
  if (tid < 128) dkl[tid] = diagk[(size_t)bh * Tn + t0 + tid];

  float zacc = 0.f;
  f32x4 kvacc[9];
#pragma unroll
  for (int i = 0; i < 9; ++i) kvacc[i] = (f32x4){0.f, 0.f, 0.f, 0.f};
  const int dtile = wv & 3, mg = wv >> 2;
  __syncthreads();

  for (int s = 0; s < 4; ++s) {
    if (s) __syncthreads();
    // P1: dd^T tiles (row=m, col=t), exp -> strip
#pragma unroll
    for (int i = 0; i < 5; ++i) {
      int idx = wv + 8 * i;
      if (idx < 36) {
        int mt = idx % 18, th = idx / 18;
        const u16* ar = &projbf[(mt * 16 + lj) * 64 + lg * 8];
        int trow = s * 32 + th * 16 + lj;
        const u16* br = &knl[trow * 72 + lg * 8];
        f32x4 z = {0.f, 0.f, 0.f, 0.f};
        z = mfma16(ldb(ar), ldb(br), z);
        z = mfma16(ldb(ar + 32), ldb(br + 32), z);
        float dgk = dkl[trow];
#pragma unroll
        for (int r = 0; r < 4; ++r) {
          int m = mt * 16 + lg * 4 + r;
          float val = (m < Mn) ? RATIO * (__expf(z[r] - dgk - kmx) + SM_EPS) : 0.f;
          strip[m * 40 + th * 16 + lj] = f2bf(val);
        }
      }
    }
    __syncthreads();
    // z partial (column sums over t of phi_k = row sums of strip)
    if (tid < MP) {
      const u16* srow = &strip[tid * 40];
#pragma unroll
      for (int o = 0; o < 32; o += 8) {
        bf16x8 vv = ldb(srow + o);
#pragma unroll
        for (int e = 0; e < 8; ++e) zacc += bf2f((u16)vv[e]);
      }
    }
    // KV^T mfma: A = V^T (row d, k=t), B = strip (col m, k=t)
    {
      bf16x8 av = ldb(&Vt[(dtile * 16 + lj) * 136 + s * 32 + lg * 8]);
#pragma unroll
      for (int i = 0; i < 9; ++i) {
        int mt = mg * 9 + i;
        kvacc[i] = mfma16(av, ldb(&strip[(mt * 16 + lj) * 40 + lg * 8]), kvacc[i]);
      }
    }
  }
  // write KV^T partial (row=d, col=m)
  size_t base = ((size_t)(bh * NC + c) * 64) * MP;
#pragma unroll
  for (int i = 0; i < 9; ++i) {
    int mt = mg * 9 + i;
#pragma unroll
    for (int r = 0; r < 4; ++r) {
      int d = dtile * 16 + lg * 4 + r;
      int m = mt * 16 + lj;
      kvT[base + (size_t)d * MP + m] = f2bf(kvacc[i][r]);
    }
  }
  if (tid < MP) zp[((size_t)bh * NC + c) * MP + tid] = zacc;
}

// ---------------- exclusive prefix scans over chunks ----------------
__global__ void scan_kv(u16* __restrict__ kvT) {
  int idx = blockIdx.x * 256 + threadIdx.x;          // 48*64*288
  if (idx >= BH * 64 * MP) return;
  int m = idx % MP;
  int r = idx / MP;
  int d = r % 64, bh = r / 64;
  u16* p = kvT + ((size_t)(bh * NC) * 64 + d) * MP + m;
  const size_t cs = (size_t)64 * MP;
  float acc = 0.f;
  for (int c = 0; c < NC; ++c) {
    float x = bf2f(p[c * cs]);
    p[c * cs] = f2bf(acc);
    acc += x;
  }
}

__global__ void scan_z(float* __restrict__ zp) {
  int idx = blockIdx.x * 256 + threadIdx.x;          // 48*288
  if (idx >= BH * MP) return;
  int m = idx % MP, bh = idx / MP;
  float* p = zp + (size_t)bh * NC * MP + m;
  float acc = 0.f;
  for (int c = 0; c < NC; ++c) {
    float x = p[(size_t)c * MP];
    p[(size_t)c * MP] = acc;
    acc += x;
  }
}

// ---------------- stage_c: A = mask(QK^T); out = (A@V + Q@S_prev) / den ----------------
__global__ __launch_bounds__(512) void stage_c(
    const float* __restrict__ v, const u16* __restrict__ kn,
    const u16* __restrict__ projbf, const float* __restrict__ diagk,
    const float* __restrict__ kmax, const u16* __restrict__ phiq,
    const u16* __restrict__ kvT, const float* __restrict__ zp,
    float* __restrict__ out) {
  __shared__ __align__(16) u16 phik[128 * 296];   // 75,776
  __shared__ __align__(16) u16 Albuf[128 * 136];  // 34,816
  __shared__ __align__(16) u16 knVt[128 * 72];    // 18,432 (kn, then V^T [64][136])
  __shared__ float zl[MP];
  __shared__ float dkl[128];
  __shared__ float rs2[128 * 8];
  __shared__ float qzb[128];
  __shared__ float den[128];

  const int tid = threadIdx.x, lane = tid & 63, wv = tid >> 6;
  const int lj = lane & 15, lg = lane >> 4;
  const int c = blockIdx.x & 31, bh = blockIdx.x >> 5;
  const int b = bh / Hn, h = bh % Hn;
  const int t0 = c * CH;
  const float kmx = kmax[bh];

#pragma unroll
  for (int l = 0; l < 2; ++l) {
    int idx = tid + l * 512;
    int t = idx >> 3, e8 = (idx & 7) * 8;
    *reinterpret_cast<uint4*>(&knVt[t * 72 + e8]) =
        *reinterpret_cast<const uint4*>(&kn[((size_t)bh * Tn + t0 + t) * 64 + e8]);
  }
  if (tid < MP) zl[tid] = zp[((size_t)bh * NC + c) * MP + tid];
  if (tid < 128) dkl[tid] = diagk[(size_t)bh * Tn + t0 + tid];
#pragma unroll
  for (int l = 0; l < 5; ++l) {   // zero Albuf (2176 uint4)
    int idx = tid + l * 512;
    if (idx < 2176)
      *reinterpret_cast<uint4*>(&Albuf[idx * 8]) = make_uint4(0, 0, 0, 0);
  }
  for (int idx = tid; idx < 128 * 8; idx += 512) rs2[idx] = 0.f;
  if (tid < 128) qzb[tid] = 0.f;
  __syncthreads();

  // P1: phi_k (row=t', col=m) -> LDS
  {
    bf16x8 a0 = ldb(&knVt[(wv * 16 + lj) * 72 + lg * 8]);
    bf16x8 a1 = ldb(&knVt[(wv * 16 + lj) * 72 + 32 + lg * 8]);
    float dgk[4];
#pragma unroll
    for (int r = 0; r < 4; ++r) dgk[r] = dkl[wv * 16 + lg * 4 + r];
#pragma unroll
    for (int mt = 0; mt < 18; ++mt) {
      const u16* br = &projbf[(mt * 16 + lj) * 64 + lg * 8];
      f32x4 z = {0.f, 0.f, 0.f, 0.f};
      z = mfma16(a0, ldb(br), z);
      z = mfma16(a1, ldb(br + 32), z);
      int m = mt * 16 + lj;
#pragma unroll
      for (int r = 0; r < 4; ++r) {
        float val = (m < Mn) ? RATIO * (__expf(z[r] - dgk[r] - kmx) + SM_EPS) : 0.f;
        phik[(wv * 16 + lg * 4 + r) * 296 + m] = f2bf(val);
      }
    }
  }
  __syncthreads();

  // stage V^T into knVt (kn dead); consumed after next barrier
  u16* Vt = knVt;
#pragma unroll
  for (int l = 0; l < 4; ++l) {
    int idx = tid + l * 512;
    int t = idx >> 4, d4 = (idx & 15) * 4;
    float4 vv = *reinterpret_cast<const float4*>(
        &v[(((size_t)b * Tn + t0 + t) * Hn + h) * 64 + d4]);
    Vt[(d4 + 0) * 136 + t] = f2bf(vv.x);
    Vt[(d4 + 1) * 136 + t] = f2bf(vv.y);
    Vt[(d4 + 2) * 136 + t] = f2bf(vv.z);
    Vt[(d4 + 3) * 136 + t] = f2bf(vv.w);
  }

  // P2: QK^T causal tiles, balanced flat list
  f32x4 qacc[5];
#pragma unroll
  for (int i = 0; i < 5; ++i) qacc[i] = (f32x4){0.f, 0.f, 0.f, 0.f};
  const size_t qbase = ((size_t)bh * Tn + t0) * MP;
  for (int ks = 0; ks < 9; ++ks) {
    int m0 = ks * 32;
#pragma unroll
    for (int i = 0; i < 5; ++i) {
      int idx = wv + 8 * i;
      if (idx < 36) {
        int tt = cTT[idx], tp = cTP[idx];
        bf16x8 af = ldb(&phiq[qbase + (size_t)(tt * 16 + lj) * MP + m0 + lg * 8]);
        bf16x8 bf = ldb(&phik[(tp * 16 + lj) * 296 + m0 + lg * 8]);
        qacc[i] = mfma16(af, bf, qacc[i]);
      }
    }
  }
#pragma unroll
  for (int i = 0; i < 5; ++i) {
    int idx = wv + 8 * i;
    if (idx < 36) {
      int tt = cTT[idx], tp = cTP[idx];
      f32x4 a = qacc[i];
      if (tt == tp) {
#pragma unroll
        for (int r = 0; r < 4; ++r)
          if (lj > lg * 4 + r) a[r] = 0.f;
      }
      f32x4 s = a;
#pragma unroll
      for (int r = 0; r < 4; ++r) {
        s[r] += __shfl_xor(s[r], 1);
        s[r] += __shfl_xor(s[r], 2);
        s[r] += __shfl_xor(s[r], 4);
        s[r] += __shfl_xor(s[r], 8);
      }
      if (lj == 0) {
#pragma unroll
        for (int r = 0; r < 4; ++r) rs2[(tt * 16 + lg * 4 + r) * 8 + tp] = s[r];
      }
#pragma unroll
      for (int r = 0; r < 4; ++r)
        Albuf[(tt * 16 + lg * 4 + r) * 136 + tp * 16 + lj] = f2bf(a[r]);
    }
  }
  __syncthreads();

  // P3: O += A @ V  (A rows of t-tile wv; triangular k-step skip)
  f32x4 oacc[4];
#pragma unroll
  for (int dt = 0; dt < 4; ++dt) oacc[dt] = (f32x4){0.f, 0.f, 0.f, 0.f};
  const int ksteps = (wv >> 1) + 1;
  for (int ks = 0; ks < ksteps; ++ks) {
    bf16x8 af = ldb(&Albuf[(wv * 16 + lj) * 136 + ks * 32 + lg * 8]);
#pragma unroll
    for (int dt = 0; dt < 4; ++dt) {
      bf16x8 bf = ldb(&Vt[(dt * 16 + lj) * 136 + ks * 32 + lg * 8]);
      oacc[dt] = mfma16(af, bf, oacc[dt]);
    }
  }

  // P4: O += phi_q @ S_prev (B = kvT rows, global), fused qz
  float qz = 0.f;
  const size_t kvbase = ((size_t)(bh * NC + c) * 64) * MP;
  for (int ks = 0; ks < 9; ++ks) {
    int m0 = ks * 32;
    bf16x8 af = ldb(&phiq[qbase + (size_t)(wv * 16 + lj) * MP + m0 + lg * 8]);
#pragma unroll
    for (int e = 0; e < 8; ++e)
      qz += bf2f((u16)af[e]) * zl[m0 + lg * 8 + e];
#pragma unroll
    for (int dt = 0; dt < 4; ++dt) {
      bf16x8 bf = ldb(&kvT[kvbase + (size_t)(dt * 16 + lj) * MP + m0 + lg * 8]);
      oacc[dt] = mfma16(af, bf, oacc[dt]);
    }
  }
  qz += __shfl_xor(qz, 16);
  qz += __shfl_xor(qz, 32);
  if (lane < 16) qzb[wv * 16 + lane] = qz;
  __syncthreads();

  if (tid < 128) {
    float s = qzb[tid] + N_EPS;
#pragma unroll
    for (int t2 = 0; t2 < 8; ++t2) s += rs2[tid * 8 + t2];
    den[tid] = s;
  }
  __syncthreads();

#pragma unroll
  for (int dt = 0; dt < 4; ++dt) {
#pragma unroll
    for (int r = 0; r < 4; ++r) {
      int tl = wv * 16 + lg * 4 + r;
      float o = oacc[dt][r] / den[tl];
      out[(((size_t)b * Tn + t0 + tl) * Hn + h) * 64 + dt * 16 + lj] = o;
    }
  }
}

extern "C" void kernel_launch(void* const* d_in, const int* in_sizes, int n_in,
                              void* d_out, int out_size, void* d_ws, size_t ws_size,
                              hipStream_t stream) {
  const float* q = (const float*)d_in[0];
  const float* k = (const float*)d_in[1];
  const float* v = (const float*)d_in[2];
  const float* proj = (const float*)d_in[3];
  float* out = (float*)d_out;

  char* ws = (char*)d_ws;
  const size_t phiq_b = (size_t)BH * Tn * MP * 2;        // 113,246,208
  const size_t kvT_b  = (size_t)BH * NC * 64 * MP * 2;   //  56,623,104
  const size_t kn_b   = (size_t)BH * Tn * 64 * 2;        //  25,165,824
  const size_t zp_b   = (size_t)BH * NC * MP * 4;        //   1,769,472
  const size_t dk_b   = (size_t)BH * Tn * 4;             //     786,432
  const size_t pj_b   = (size_t)MP * 64 * 2;             //      36,864

  u16*   phiq  = (u16*)ws;
  u16*   kvT   = (u16*)(ws + phiq_b);
  u16*   kn    = (u16*)(ws + phiq_b + kvT_b);
  float* zp    = (float*)(ws + phiq_b + kvT_b + kn_b);
  float* diagk = (float*)(ws + phiq_b + kvT_b + kn_b + zp_b);
  u16*   projbf= (u16*)(ws + phiq_b + kvT_b + kn_b + zp_b + dk_b);
  float* kmax  = (float*)(ws + phiq_b + kvT_b + kn_b + zp_b + dk_b + pj_b);

  prep<<<72, 256, 0, stream>>>(proj, projbf, kmax);
  feat_k<<<BH * 64, 256, 0, stream>>>(k, projbf, kn, diagk, kmax);
  feat_q<<<BH * 64, 256, 0, stream>>>(q, projbf, phiq);
  stage_a<<<BH * NC, 512, 0, stream>>>(v, kn, projbf, diagk, kmax, kvT, zp);
  scan_kv<<<(BH * 64 * MP) / 256, 256, 0, stream>>>(kvT);
  scan_z<<<(BH * MP + 255) / 256, 256, 0, stream>>>(zp);
  stage_c<<<BH * NC, 512, 0, stream>>>(v, kn, projbf, diagk, kmax, phiq, kvT, zp, out);
}

// Round 4
// 389.620 us; speedup vs baseline: 4.3885x; 1.0717x over previous
//
#include <hip/hip_runtime.h>
#include <hip/hip_bf16.h>

// Performer causal attention, chunked scan, MFMA bf16 everywhere.
// B=4 T=4096 H=12 E=64 M=266 (padded 288). mfma_f32_16x16x32_bf16.
// R3: stage_c restructured to quarter-strip phi_k -> 63.6KB LDS -> 2 blocks/CU.

typedef unsigned short u16;
typedef __attribute__((ext_vector_type(8))) short bf16x8;   // 8 bf16 = 4 VGPR
typedef __attribute__((ext_vector_type(4))) float f32x4;

constexpr int Tn = 4096, Hn = 12;
constexpr int MP = 288;       // padded feature dim
constexpr int Mn = 266;
constexpr int CH = 128;       // chunk length
constexpr int NC = 32;        // chunks
constexpr int BH = 48;

constexpr float DATA_NORM = 0.35355339059327379f;  // 64^-0.25
constexpr float SM_EPS = 1e-4f;
constexpr float N_EPS  = 1e-6f;
constexpr float RATIO  = 0.06131393152401153f;     // 266^-0.5

// causal tiles (tt,tp) tp<=tt, grouped by tp-quarter (tp/2), wave-balanced order
__constant__ signed char qTT[36] = {0,1,2,3,4,5,6,7,1,2,3,4,5,6,7,
                                    2,3,4,5,6,7,3,4,5,6,7,
                                    4,5,6,7,5,6,7,
                                    6,7,7};
__constant__ signed char qTP[36] = {0,0,0,0,0,0,0,0,1,1,1,1,1,1,1,
                                    2,2,2,2,2,2,3,3,3,3,3,
                                    4,4,4,4,5,5,5,
                                    6,6,7};
__constant__ int qOFF[5] = {0, 15, 26, 33, 36};

__device__ __forceinline__ u16 f2bf(float f) {
  __hip_bfloat16 h = __float2bfloat16(f);
  return __builtin_bit_cast(u16, h);
}
__device__ __forceinline__ float bf2f(u16 u) {
  return __uint_as_float(((unsigned)u) << 16);
}
__device__ __forceinline__ bf16x8 ldb(const u16* p) {
  return *reinterpret_cast<const bf16x8*>(p);
}
__device__ __forceinline__ f32x4 mfma16(bf16x8 a, bf16x8 b, f32x4 c) {
  return __builtin_amdgcn_mfma_f32_16x16x32_bf16(a, b, c, 0, 0, 0);
}
__device__ __forceinline__ void atomicMaxF(float* addr, float val) {
  if (val >= 0.f) atomicMax(reinterpret_cast<int*>(addr), __float_as_int(val));
  else atomicMin(reinterpret_cast<unsigned int*>(addr), __float_as_uint(val));
}

// ---------------- prep: projbf [288][64] bf16 zero-padded; kmax init ----------------
__global__ void prep(const float* __restrict__ proj, u16* __restrict__ projbf,
                     float* __restrict__ kmax) {
  int idx = blockIdx.x * 256 + threadIdx.x;
  if (idx < MP * 64) {
    int m = idx >> 6, e = idx & 63;
    float v = (m < Mn) ? proj[m * 64 + e] : 0.f;
    projbf[idx] = f2bf(v);
  }
  if (blockIdx.x == 0 && threadIdx.x < BH) kmax[threadIdx.x] = -3.0e38f;
}

// ---------------- feat_q: phi_q = ratio*(exp(dd - diag - rowmax) + eps) ----------------
__global__ __launch_bounds__(256) void feat_q(
    const float* __restrict__ q, const u16* __restrict__ projbf,
    u16* __restrict__ phiq) {
  __shared__ __align__(16) u16 xt[64 * 72];
  __shared__ float diag[64];
  const int tid = threadIdx.x;
  const int bh = blockIdx.x >> 6, tb = blockIdx.x & 63;
  const int b = bh / Hn, h = bh % Hn;
  const int t0 = tb * 64;
  {
    const int t = tid >> 2, e0 = (tid & 3) * 16;
    const float* row = q + (((size_t)b * Tn + t0 + t) * Hn + h) * 64 + e0;
    float ss = 0.f;
#pragma unroll
    for (int q4 = 0; q4 < 4; ++q4) {
      float4 vv = *reinterpret_cast<const float4*>(row + q4 * 4);
      float x0 = vv.x * DATA_NORM, x1 = vv.y * DATA_NORM;
      float x2 = vv.z * DATA_NORM, x3 = vv.w * DATA_NORM;
      ss += x0 * x0 + x1 * x1 + x2 * x2 + x3 * x3;
      ushort4 uu = make_ushort4(f2bf(x0), f2bf(x1), f2bf(x2), f2bf(x3));
      *reinterpret_cast<ushort4*>(&xt[t * 72 + e0 + q4 * 4]) = uu;
    }
    ss += __shfl_xor(ss, 1);
    ss += __shfl_xor(ss, 2);
    if ((tid & 3) == 0) diag[t] = 0.5f * ss;
  }
  __syncthreads();
  const int lane = tid & 63, wv = tid >> 6;
  const int lj = lane & 15, lg = lane >> 4;
  bf16x8 a0 = ldb(&xt[(wv * 16 + lj) * 72 + lg * 8]);
  bf16x8 a1 = ldb(&xt[(wv * 16 + lj) * 72 + 32 + lg * 8]);
  f32x4 acc[17];
#pragma unroll
  for (int mt = 0; mt < 17; ++mt) {
    const u16* br = &projbf[(mt * 16 + lj) * 64 + lg * 8];
    f32x4 z = {0.f, 0.f, 0.f, 0.f};
    z = mfma16(a0, ldb(br), z);
    z = mfma16(a1, ldb(br + 32), z);
    acc[mt] = z;
  }
  float rmax[4] = {-3e38f, -3e38f, -3e38f, -3e38f};
#pragma unroll
  for (int mt = 0; mt < 17; ++mt) {
    int m = mt * 16 + lj;
    if (m < Mn) {
#pragma unroll
      for (int r = 0; r < 4; ++r) rmax[r] = fmaxf(rmax[r], acc[mt][r]);
    }
  }
#pragma unroll
  for (int r = 0; r < 4; ++r) {
    rmax[r] = fmaxf(rmax[r], __shfl_xor(rmax[r], 1));
    rmax[r] = fmaxf(rmax[r], __shfl_xor(rmax[r], 2));
    rmax[r] = fmaxf(rmax[r], __shfl_xor(rmax[r], 4));
    rmax[r] = fmaxf(rmax[r], __shfl_xor(rmax[r], 8));
  }
  float dg[4];
#pragma unroll
  for (int r = 0; r < 4; ++r) dg[r] = diag[wv * 16 + lg * 4 + r];
  u16* ob = phiq + ((size_t)bh * Tn + t0 + wv * 16) * MP;
#pragma unroll
  for (int mt = 0; mt < 17; ++mt) {
    int m = mt * 16 + lj;
#pragma unroll
    for (int r = 0; r < 4; ++r) {
      float val = 0.f;
      if (m < Mn)
        val = RATIO * (__expf(acc[mt][r] - dg[r] - rmax[r]) + SM_EPS);
      ob[(size_t)(lg * 4 + r) * MP + m] = f2bf(val);
    }
  }
#pragma unroll
  for (int r = 0; r < 4; ++r)   // m-tile 17 = all pad -> zeros
    ob[(size_t)(lg * 4 + r) * MP + 272 + lj] = 0;
}

// ---------------- feat_k: global max of dd; emit kn (bf16 x~) + diagk ----------------
__global__ __launch_bounds__(256) void feat_k(
    const float* __restrict__ k, const u16* __restrict__ projbf,
    u16* __restrict__ kn, float* __restrict__ diagk, float* __restrict__ kmax) {
  __shared__ __align__(16) u16 xt[64 * 72];
  __shared__ float wred[4];
  const int tid = threadIdx.x;
  const int bh = blockIdx.x >> 6, tb = blockIdx.x & 63;
  const int b = bh / Hn, h = bh % Hn;
  const int t0 = tb * 64;
  {
    const int t = tid >> 2, e0 = (tid & 3) * 16;
    const float* row = k + (((size_t)b * Tn + t0 + t) * Hn + h) * 64 + e0;
    u16* knr = kn + ((size_t)bh * Tn + t0 + t) * 64 + e0;
    float ss = 0.f;
#pragma unroll
    for (int q4 = 0; q4 < 4; ++q4) {
      float4 vv = *reinterpret_cast<const float4*>(row + q4 * 4);
      float x0 = vv.x * DATA_NORM, x1 = vv.y * DATA_NORM;
      float x2 = vv.z * DATA_NORM, x3 = vv.w * DATA_NORM;
      ss += x0 * x0 + x1 * x1 + x2 * x2 + x3 * x3;
      ushort4 uu = make_ushort4(f2bf(x0), f2bf(x1), f2bf(x2), f2bf(x3));
      *reinterpret_cast<ushort4*>(&xt[t * 72 + e0 + q4 * 4]) = uu;
      *reinterpret_cast<ushort4*>(knr + q4 * 4) = uu;
    }
    ss += __shfl_xor(ss, 1);
    ss += __shfl_xor(ss, 2);
    if ((tid & 3) == 0) diagk[(size_t)bh * Tn + t0 + t] = 0.5f * ss;
  }
  __syncthreads();
  const int lane = tid & 63, wv = tid >> 6;
  const int lj = lane & 15, lg = lane >> 4;
  bf16x8 a0 = ldb(&xt[(wv * 16 + lj) * 72 + lg * 8]);
  bf16x8 a1 = ldb(&xt[(wv * 16 + lj) * 72 + 32 + lg * 8]);
  float mx = -3e38f;
#pragma unroll
  for (int mt = 0; mt < 17; ++mt) {
    const u16* br = &projbf[(mt * 16 + lj) * 64 + lg * 8];
    f32x4 z = {0.f, 0.f, 0.f, 0.f};
    z = mfma16(a0, ldb(br), z);
    z = mfma16(a1, ldb(br + 32), z);
    int m = mt * 16 + lj;
    if (m < Mn)
      mx = fmaxf(mx, fmaxf(fmaxf(z[0], z[1]), fmaxf(z[2], z[3])));
  }
  mx = fmaxf(mx, __shfl_xor(mx, 1));
  mx = fmaxf(mx, __shfl_xor(mx, 2));
  mx = fmaxf(mx, __shfl_xor(mx, 4));
  mx = fmaxf(mx, __shfl_xor(mx, 8));
  mx = fmaxf(mx, __shfl_xor(mx, 16));
  mx = fmaxf(mx, __shfl_xor(mx, 32));
  if (lane == 0) wred[wv] = mx;
  __syncthreads();
  if (tid == 0)
    atomicMaxF(&kmax[bh], fmaxf(fmaxf(wred[0], wred[1]), fmaxf(wred[2], wred[3])));
}

// ---------------- stage_a: KV^T partial = V^T @ phi_k per chunk + z partial ----------------
__global__ __launch_bounds__(512) void stage_a(
    const float* __restrict__ v, const u16* __restrict__ kn,
    const u16* __restrict__ projbf, const float* __restrict__ diagk,
    const float* __restrict__ kmax, u16* __restrict__ kvT,
    float* __restrict__ zp) {
  __shared__ __align__(16) u16 knl[128 * 72];     // 18,432
  __shared__ __align__(16) u16 Vt[64 * 136];      // 17,408  (V^T [d][t])
  __shared__ __align__(16) u16 strip[288 * 40];   // 23,040  (phi_k^T [m][t-strip 32])
  __shared__ float dkl[128];
  const int tid = threadIdx.x, lane = tid & 63, wv = tid >> 6;
  const int lj = lane & 15, lg = lane >> 4;
  const int c = blockIdx.x & 31, bh = blockIdx.x >> 5;
  const int b = bh / Hn, h = bh % Hn;
  const int t0 = c * CH;
  const float kmx = kmax[bh];

#pragma unroll
  for (int l = 0; l < 2; ++l) {   // kn tile -> LDS
    int idx = tid + l * 512;
    int t = idx >> 3, e8 = (idx & 7) * 8;
    *reinterpret_cast<uint4*>(&knl[t * 72 + e8]) =
        *reinterpret_cast<const uint4*>(&kn[((size_t)bh * Tn + t0 + t) * 64 + e8]);
  }
#pragma unroll
  for (int l = 0; l < 4; ++l) {   // V -> V^T LDS bf16
    int idx = tid + l * 512;
    int t = idx >> 4, d4 = (idx & 15) * 4;
    float4 vv = *reinterpret_cast<const float4*>(
        &v[(((size_t)b * Tn + t0 + t) * Hn + h) * 64 + d4]);
    Vt[(d4 + 0) * 136 + t] = f2bf(vv.x);
    Vt[(d4 + 1) * 136 + t] = f2bf(vv.y);
    Vt[(d4 + 2) * 136 + t] = f2bf(vv.z);
    Vt[(d4 + 3) * 136 + t] = f2bf(vv.w);
  }
  if (tid < 128) dkl[tid] = diagk[(size_t)bh * Tn + t0 + tid];

  float zacc = 0.f;
  f32x4 kvacc[9];
#pragma unroll
  for (int i = 0; i < 9; ++i) kvacc[i] = (f32x4){0.f, 0.f, 0.f, 0.f};
  const int dtile = wv & 3, mg = wv >> 2;
  __syncthreads();

  for (int s = 0; s < 4; ++s) {
    if (s) __syncthreads();
    // P1: dd^T tiles (row=m, col=t), exp -> strip
#pragma unroll
    for (int i = 0; i < 5; ++i) {
      int idx = wv + 8 * i;
      if (idx < 36) {
        int mt = idx % 18, th = idx / 18;
        const u16* ar = &projbf[(mt * 16 + lj) * 64 + lg * 8];
        int trow = s * 32 + th * 16 + lj;
        const u16* br = &knl[trow * 72 + lg * 8];
        f32x4 z = {0.f, 0.f, 0.f, 0.f};
        z = mfma16(ldb(ar), ldb(br), z);
        z = mfma16(ldb(ar + 32), ldb(br + 32), z);
        float dgk = dkl[trow];
#pragma unroll
        for (int r = 0; r < 4; ++r) {
          int m = mt * 16 + lg * 4 + r;
          float val = (m < Mn) ? RATIO * (__expf(z[r] - dgk - kmx) + SM_EPS) : 0.f;
          strip[m * 40 + th * 16 + lj] = f2bf(val);
        }
      }
    }
    __syncthreads();
    // z partial (column sums over t of phi_k = row sums of strip)
    if (tid < MP) {
      const u16* srow = &strip[tid * 40];
#pragma unroll
      for (int o = 0; o < 32; o += 8) {
        bf16x8 vv = ldb(srow + o);
#pragma unroll
        for (int e = 0; e < 8; ++e) zacc += bf2f((u16)vv[e]);
      }
    }
    // KV^T mfma: A = V^T (row d, k=t), B = strip (col m, k=t)
    {
      bf16x8 av = ldb(&Vt[(dtile * 16 + lj) * 136 + s * 32 + lg * 8]);
#pragma unroll
      for (int i = 0; i < 9; ++i) {
        int mt = mg * 9 + i;
        kvacc[i] = mfma16(av, ldb(&strip[(mt * 16 + lj) * 40 + lg * 8]), kvacc[i]);
      }
    }
  }
  // write KV^T partial (row=d, col=m)
  size_t base = ((size_t)(bh * NC + c) * 64) * MP;
#pragma unroll
  for (int i = 0; i < 9; ++i) {
    int mt = mg * 9 + i;
#pragma unroll
    for (int r = 0; r < 4; ++r) {
      int d = dtile * 16 + lg * 4 + r;
      int m = mt * 16 + lj;
      kvT[base + (size_t)d * MP + m] = f2bf(kvacc[i][r]);
    }
  }
  if (tid < MP) zp[((size_t)bh * NC + c) * MP + tid] = zacc;
}

// ---------------- exclusive prefix scans over chunks ----------------
__global__ void scan_kv(u16* __restrict__ kvT) {
  int idx = blockIdx.x * 256 + threadIdx.x;          // 48*64*288
  if (idx >= BH * 64 * MP) return;
  int m = idx % MP;
  int r = idx / MP;
  int d = r % 64, bh = r / 64;
  u16* p = kvT + ((size_t)(bh * NC) * 64 + d) * MP + m;
  const size_t cs = (size_t)64 * MP;
  float acc = 0.f;
  for (int c = 0; c < NC; ++c) {
    float x = bf2f(p[c * cs]);
    p[c * cs] = f2bf(acc);
    acc += x;
  }
}

__global__ void scan_z(float* __restrict__ zp) {
  int idx = blockIdx.x * 256 + threadIdx.x;          // 48*288
  if (idx >= BH * MP) return;
  int m = idx % MP, bh = idx / MP;
  float* p = zp + (size_t)bh * NC * MP + m;
  float acc = 0.f;
  for (int c = 0; c < NC; ++c) {
    float x = p[(size_t)c * MP];
    p[(size_t)c * MP] = acc;
    acc += x;
  }
}

// ---------------- stage_c v2: quarter-strip phi_k; 2 blocks/CU ----------------
// A = mask(QK^T); out = (A@V + Q@S_prev) / (rowsum(A) + q.z_prev + eps)
__global__ __launch_bounds__(512, 4) void stage_c(
    const float* __restrict__ v, const u16* __restrict__ kn,
    const u16* __restrict__ projbf, const float* __restrict__ diagk,
    const float* __restrict__ kmax, const u16* __restrict__ phiq,
    const u16* __restrict__ kvT, const float* __restrict__ zp,
    float* __restrict__ out) {
  __shared__ __align__(16) u16 Albuf[128 * 136];          // 34,816
  __shared__ __align__(16) u16 arena[32 * 296 + 32 * 72]; // 23,552 (phik_q + knq; Vt later)
  __shared__ float zl[MP];
  __shared__ float dkl[128];
  __shared__ float rs2[128 * 8];
  __shared__ float qzb[128];
  __shared__ float den[128];

  u16* phik_q = arena;              // [32][296]
  u16* knq    = arena + 32 * 296;   // [32][72]

  const int tid = threadIdx.x, lane = tid & 63, wv = tid >> 6;
  const int lj = lane & 15, lg = lane >> 4;
  const int c = blockIdx.x & 31, bh = blockIdx.x >> 5;
  const int b = bh / Hn, h = bh % Hn;
  const int t0 = c * CH;
  const float kmx = kmax[bh];
  const size_t qbase = ((size_t)bh * Tn + t0) * MP;

  if (tid < MP) zl[tid] = zp[((size_t)bh * NC + c) * MP + tid];
  if (tid < 128) dkl[tid] = diagk[(size_t)bh * Tn + t0 + tid];
#pragma unroll
  for (int l = 0; l < 5; ++l) {   // zero Albuf (2176 uint4)
    int idx = tid + l * 512;
    if (idx < 2176)
      *reinterpret_cast<uint4*>(&Albuf[idx * 8]) = make_uint4(0, 0, 0, 0);
  }
  for (int idx = tid; idx < 128 * 8; idx += 512) rs2[idx] = 0.f;

  for (int qq = 0; qq < 4; ++qq) {
    // load kn rows for this quarter (32 rows x 64 e)
    if (tid < 256) {
      int t = tid >> 3, e8 = (tid & 7) * 8;
      *reinterpret_cast<uint4*>(&knq[t * 72 + e8]) =
          *reinterpret_cast<const uint4*>(
              &kn[((size_t)bh * Tn + t0 + qq * 32 + t) * 64 + e8]);
    }
    __syncthreads();

    // P1: phi_k for quarter -> phik_q [32][296]; 36 units (2 t-tiles x 18 m-tiles)
    for (int u = wv; u < 36; u += 8) {
      int t2 = u / 18, mt = u % 18;
      bf16x8 a0 = ldb(&knq[(t2 * 16 + lj) * 72 + lg * 8]);
      bf16x8 a1 = ldb(&knq[(t2 * 16 + lj) * 72 + 32 + lg * 8]);
      const u16* br = &projbf[(mt * 16 + lj) * 64 + lg * 8];
      f32x4 z = {0.f, 0.f, 0.f, 0.f};
      z = mfma16(a0, ldb(br), z);
      z = mfma16(a1, ldb(br + 32), z);
      int m = mt * 16 + lj;
      int tq = t2 * 16 + lg * 4;
#pragma unroll
      for (int r = 0; r < 4; ++r) {
        float val = (m < Mn)
            ? RATIO * (__expf(z[r] - dkl[qq * 32 + tq + r] - kmx) + SM_EPS) : 0.f;
        phik_q[(tq + r) * 296 + m] = f2bf(val);
      }
    }
    __syncthreads();

    // P2: causal QK^T tiles with tp in this quarter; <=2 tiles per wave, interleaved
    const int beg = qOFF[qq], end = qOFF[qq + 1];
    const int ia = beg + wv, ib = beg + wv + 8;
    const bool ha = ia < end, hb = ib < end;
    const int tta = ha ? qTT[ia] : 0, tpa = ha ? qTP[ia] : 0;
    const int ttb = hb ? qTT[ib] : 0, tpb = hb ? qTP[ib] : 0;
    f32x4 accA = {0.f, 0.f, 0.f, 0.f}, accB = {0.f, 0.f, 0.f, 0.f};
    if (ha) {
#pragma unroll
      for (int ks = 0; ks < 9; ++ks) {
        int m0 = ks * 32;
        accA = mfma16(ldb(&phiq[qbase + (size_t)(tta * 16 + lj) * MP + m0 + lg * 8]),
                      ldb(&phik_q[((tpa & 1) * 16 + lj) * 296 + m0 + lg * 8]), accA);
        if (hb)
          accB = mfma16(ldb(&phiq[qbase + (size_t)(ttb * 16 + lj) * MP + m0 + lg * 8]),
                        ldb(&phik_q[((tpb & 1) * 16 + lj) * 296 + m0 + lg * 8]), accB);
      }
      // finalize A-tile(s): mask, rowsum, store
#pragma unroll
      for (int pick = 0; pick < 2; ++pick) {
        if (pick == 1 && !hb) break;
        int tt = pick ? ttb : tta, tp = pick ? tpb : tpa;
        f32x4 a = pick ? accB : accA;
        if (tt == tp) {
#pragma unroll
          for (int r = 0; r < 4; ++r)
            if (lj > lg * 4 + r) a[r] = 0.f;
        }
        f32x4 s = a;
#pragma unroll
        for (int r = 0; r < 4; ++r) {
          s[r] += __shfl_xor(s[r], 1);
          s[r] += __shfl_xor(s[r], 2);
          s[r] += __shfl_xor(s[r], 4);
          s[r] += __shfl_xor(s[r], 8);
        }
        if (lj == 0) {
#pragma unroll
          for (int r = 0; r < 4; ++r) rs2[(tt * 16 + lg * 4 + r) * 8 + tp] = s[r];
        }
#pragma unroll
        for (int r = 0; r < 4; ++r)
          Albuf[(tt * 16 + lg * 4 + r) * 136 + tp * 16 + lj] = f2bf(a[r]);
      }
    }
    __syncthreads();
  }

  // stage V^T [64][136] into arena (phik_q/knq dead)
  u16* Vt = arena;
#pragma unroll
  for (int l = 0; l < 4; ++l) {
    int idx = tid + l * 512;
    int t = idx >> 4, d4 = (idx & 15) * 4;
    float4 vv = *reinterpret_cast<const float4*>(
        &v[(((size_t)b * Tn + t0 + t) * Hn + h) * 64 + d4]);
    Vt[(d4 + 0) * 136 + t] = f2bf(vv.x);
    Vt[(d4 + 1) * 136 + t] = f2bf(vv.y);
    Vt[(d4 + 2) * 136 + t] = f2bf(vv.z);
    Vt[(d4 + 3) * 136 + t] = f2bf(vv.w);
  }
  __syncthreads();

  // P3: O += A @ V (triangular k-step skip)
  f32x4 oacc[4];
#pragma unroll
  for (int dt = 0; dt < 4; ++dt) oacc[dt] = (f32x4){0.f, 0.f, 0.f, 0.f};
  const int ksteps = (wv >> 1) + 1;
  for (int ks = 0; ks < ksteps; ++ks) {
    bf16x8 af = ldb(&Albuf[(wv * 16 + lj) * 136 + ks * 32 + lg * 8]);
#pragma unroll
    for (int dt = 0; dt < 4; ++dt) {
      bf16x8 bf = ldb(&Vt[(dt * 16 + lj) * 136 + ks * 32 + lg * 8]);
      oacc[dt] = mfma16(af, bf, oacc[dt]);
    }
  }

  // P4: O += phi_q @ S_prev (kvT global), fused qz
  float qz = 0.f;
  const size_t kvbase = ((size_t)(bh * NC + c) * 64) * MP;
#pragma unroll
  for (int ks = 0; ks < 9; ++ks) {
    int m0 = ks * 32;
    bf16x8 af = ldb(&phiq[qbase + (size_t)(wv * 16 + lj) * MP + m0 + lg * 8]);
#pragma unroll
    for (int e = 0; e < 8; ++e)
      qz += bf2f((u16)af[e]) * zl[m0 + lg * 8 + e];
#pragma unroll
    for (int dt = 0; dt < 4; ++dt) {
      bf16x8 bf = ldb(&kvT[kvbase + (size_t)(dt * 16 + lj) * MP + m0 + lg * 8]);
      oacc[dt] = mfma16(af, bf, oacc[dt]);
    }
  }
  qz += __shfl_xor(qz, 16);
  qz += __shfl_xor(qz, 32);
  if (lane < 16) qzb[wv * 16 + lane] = qz;
  __syncthreads();

  if (tid < 128) {
    float s = qzb[tid] + N_EPS;
#pragma unroll
    for (int t2 = 0; t2 < 8; ++t2) s += rs2[tid * 8 + t2];
    den[tid] = s;
  }
  __syncthreads();

#pragma unroll
  for (int dt = 0; dt < 4; ++dt) {
#pragma unroll
    for (int r = 0; r < 4; ++r) {
      int tl = wv * 16 + lg * 4 + r;
      float o = oacc[dt][r] / den[tl];
      out[(((size_t)b * Tn + t0 + tl) * Hn + h) * 64 + dt * 16 + lj] = o;
    }
  }
}

extern "C" void kernel_launch(void* const* d_in, const int* in_sizes, int n_in,
                              void* d_out, int out_size, void* d_ws, size_t ws_size,
                              hipStream_t stream) {
  const float* q = (const float*)d_in[0];
  const float* k = (const float*)d_in[1];
  const float* v = (const float*)d_in[2];
  const float* proj = (const float*)d_in[3];
  float* out = (float*)d_out;

  char* ws = (char*)d_ws;
  const size_t phiq_b = (size_t)BH * Tn * MP * 2;        // 113,246,208
  const size_t kvT_b  = (size_t)BH * NC * 64 * MP * 2;   //  56,623,104
  const size_t kn_b   = (size_t)BH * Tn * 64 * 2;        //  25,165,824
  const size_t zp_b   = (size_t)BH * NC * MP * 4;        //   1,769,472
  const size_t dk_b   = (size_t)BH * Tn * 4;             //     786,432
  const size_t pj_b   = (size_t)MP * 64 * 2;             //      36,864

  u16*   phiq  = (u16*)ws;
  u16*   kvT   = (u16*)(ws + phiq_b);
  u16*   kn    = (u16*)(ws + phiq_b + kvT_b);
  float* zp    = (float*)(ws + phiq_b + kvT_b + kn_b);
  float* diagk = (float*)(ws + phiq_b + kvT_b + kn_b + zp_b);
  u16*   projbf= (u16*)(ws + phiq_b + kvT_b + kn_b + zp_b + dk_b);
  float* kmax  = (float*)(ws + phiq_b + kvT_b + kn_b + zp_b + dk_b + pj_b);

  prep<<<72, 256, 0, stream>>>(proj, projbf, kmax);
  feat_k<<<BH * 64, 256, 0, stream>>>(k, projbf, kn, diagk, kmax);
  feat_q<<<BH * 64, 256, 0, stream>>>(q, projbf, phiq);
  stage_a<<<BH * NC, 512, 0, stream>>>(v, kn, projbf, diagk, kmax, kvT, zp);
  scan_kv<<<(BH * 64 * MP) / 256, 256, 0, stream>>>(kvT);
  scan_z<<<(BH * MP + 255) / 256, 256, 0, stream>>>(zp);
  stage_c<<<BH * NC, 512, 0, stream>>>(v, kn, projbf, diagk, kmax, phiq, kvT, zp, out);
}

// Round 5
// 359.544 us; speedup vs baseline: 4.7556x; 1.0837x over previous
//
#include <hip/hip_runtime.h>
#include <hip/hip_bf16.h>

// Performer causal attention, chunked scan, MFMA bf16 everywhere.
// B=4 T=4096 H=12 E=64 M=266 (padded 288). mfma_f32_16x16x32_bf16.
// R3: stage_c quarter-strip phi_k -> 63.6KB LDS -> 2 blocks/CU.
// R4: stage_c register-prefetch of phiq/kvT fragments (latency x parallelism fix).

typedef unsigned short u16;
typedef __attribute__((ext_vector_type(8))) short bf16x8;   // 8 bf16 = 4 VGPR
typedef __attribute__((ext_vector_type(4))) float f32x4;

constexpr int Tn = 4096, Hn = 12;
constexpr int MP = 288;       // padded feature dim
constexpr int Mn = 266;
constexpr int CH = 128;       // chunk length
constexpr int NC = 32;        // chunks
constexpr int BH = 48;

constexpr float DATA_NORM = 0.35355339059327379f;  // 64^-0.25
constexpr float SM_EPS = 1e-4f;
constexpr float N_EPS  = 1e-6f;
constexpr float RATIO  = 0.06131393152401153f;     // 266^-0.5

// causal tiles (tt,tp) tp<=tt, grouped by tp-quarter (tp/2), wave-balanced order
__constant__ signed char qTT[36] = {0,1,2,3,4,5,6,7,1,2,3,4,5,6,7,
                                    2,3,4,5,6,7,3,4,5,6,7,
                                    4,5,6,7,5,6,7,
                                    6,7,7};
__constant__ signed char qTP[36] = {0,0,0,0,0,0,0,0,1,1,1,1,1,1,1,
                                    2,2,2,2,2,2,3,3,3,3,3,
                                    4,4,4,4,5,5,5,
                                    6,6,7};
__constant__ int qOFF[5] = {0, 15, 26, 33, 36};

__device__ __forceinline__ u16 f2bf(float f) {
  __hip_bfloat16 h = __float2bfloat16(f);
  return __builtin_bit_cast(u16, h);
}
__device__ __forceinline__ float bf2f(u16 u) {
  return __uint_as_float(((unsigned)u) << 16);
}
__device__ __forceinline__ bf16x8 ldb(const u16* p) {
  return *reinterpret_cast<const bf16x8*>(p);
}
__device__ __forceinline__ f32x4 mfma16(bf16x8 a, bf16x8 b, f32x4 c) {
  return __builtin_amdgcn_mfma_f32_16x16x32_bf16(a, b, c, 0, 0, 0);
}
__device__ __forceinline__ void atomicMaxF(float* addr, float val) {
  if (val >= 0.f) atomicMax(reinterpret_cast<int*>(addr), __float_as_int(val));
  else atomicMin(reinterpret_cast<unsigned int*>(addr), __float_as_uint(val));
}

// ---------------- prep: projbf [288][64] bf16 zero-padded; kmax init ----------------
__global__ void prep(const float* __restrict__ proj, u16* __restrict__ projbf,
                     float* __restrict__ kmax) {
  int idx = blockIdx.x * 256 + threadIdx.x;
  if (idx < MP * 64) {
    int m = idx >> 6, e = idx & 63;
    float v = (m < Mn) ? proj[m * 64 + e] : 0.f;
    projbf[idx] = f2bf(v);
  }
  if (blockIdx.x == 0 && threadIdx.x < BH) kmax[threadIdx.x] = -3.0e38f;
}

// ---------------- feat_q: phi_q = ratio*(exp(dd - diag - rowmax) + eps) ----------------
__global__ __launch_bounds__(256) void feat_q(
    const float* __restrict__ q, const u16* __restrict__ projbf,
    u16* __restrict__ phiq) {
  __shared__ __align__(16) u16 xt[64 * 72];
  __shared__ float diag[64];
  const int tid = threadIdx.x;
  const int bh = blockIdx.x >> 6, tb = blockIdx.x & 63;
  const int b = bh / Hn, h = bh % Hn;
  const int t0 = tb * 64;
  {
    const int t = tid >> 2, e0 = (tid & 3) * 16;
    const float* row = q + (((size_t)b * Tn + t0 + t) * Hn + h) * 64 + e0;
    float ss = 0.f;
#pragma unroll
    for (int q4 = 0; q4 < 4; ++q4) {
      float4 vv = *reinterpret_cast<const float4*>(row + q4 * 4);
      float x0 = vv.x * DATA_NORM, x1 = vv.y * DATA_NORM;
      float x2 = vv.z * DATA_NORM, x3 = vv.w * DATA_NORM;
      ss += x0 * x0 + x1 * x1 + x2 * x2 + x3 * x3;
      ushort4 uu = make_ushort4(f2bf(x0), f2bf(x1), f2bf(x2), f2bf(x3));
      *reinterpret_cast<ushort4*>(&xt[t * 72 + e0 + q4 * 4]) = uu;
    }
    ss += __shfl_xor(ss, 1);
    ss += __shfl_xor(ss, 2);
    if ((tid & 3) == 0) diag[t] = 0.5f * ss;
  }
  __syncthreads();
  const int lane = tid & 63, wv = tid >> 6;
  const int lj = lane & 15, lg = lane >> 4;
  bf16x8 a0 = ldb(&xt[(wv * 16 + lj) * 72 + lg * 8]);
  bf16x8 a1 = ldb(&xt[(wv * 16 + lj) * 72 + 32 + lg * 8]);
  f32x4 acc[17];
#pragma unroll
  for (int mt = 0; mt < 17; ++mt) {
    const u16* br = &projbf[(mt * 16 + lj) * 64 + lg * 8];
    f32x4 z = {0.f, 0.f, 0.f, 0.f};
    z = mfma16(a0, ldb(br), z);
    z = mfma16(a1, ldb(br + 32), z);
    acc[mt] = z;
  }
  float rmax[4] = {-3e38f, -3e38f, -3e38f, -3e38f};
#pragma unroll
  for (int mt = 0; mt < 17; ++mt) {
    int m = mt * 16 + lj;
    if (m < Mn) {
#pragma unroll
      for (int r = 0; r < 4; ++r) rmax[r] = fmaxf(rmax[r], acc[mt][r]);
    }
  }
#pragma unroll
  for (int r = 0; r < 4; ++r) {
    rmax[r] = fmaxf(rmax[r], __shfl_xor(rmax[r], 1));
    rmax[r] = fmaxf(rmax[r], __shfl_xor(rmax[r], 2));
    rmax[r] = fmaxf(rmax[r], __shfl_xor(rmax[r], 4));
    rmax[r] = fmaxf(rmax[r], __shfl_xor(rmax[r], 8));
  }
  float dg[4];
#pragma unroll
  for (int r = 0; r < 4; ++r) dg[r] = diag[wv * 16 + lg * 4 + r];
  u16* ob = phiq + ((size_t)bh * Tn + t0 + wv * 16) * MP;
#pragma unroll
  for (int mt = 0; mt < 17; ++mt) {
    int m = mt * 16 + lj;
#pragma unroll
    for (int r = 0; r < 4; ++r) {
      float val = 0.f;
      if (m < Mn)
        val = RATIO * (__expf(acc[mt][r] - dg[r] - rmax[r]) + SM_EPS);
      ob[(size_t)(lg * 4 + r) * MP + m] = f2bf(val);
    }
  }
#pragma unroll
  for (int r = 0; r < 4; ++r)   // m-tile 17 = all pad -> zeros
    ob[(size_t)(lg * 4 + r) * MP + 272 + lj] = 0;
}

// ---------------- feat_k: global max of dd; emit kn (bf16 x~) + diagk ----------------
__global__ __launch_bounds__(256) void feat_k(
    const float* __restrict__ k, const u16* __restrict__ projbf,
    u16* __restrict__ kn, float* __restrict__ diagk, float* __restrict__ kmax) {
  __shared__ __align__(16) u16 xt[64 * 72];
  __shared__ float wred[4];
  const int tid = threadIdx.x;
  const int bh = blockIdx.x >> 6, tb = blockIdx.x & 63;
  const int b = bh / Hn, h = bh % Hn;
  const int t0 = tb * 64;
  {
    const int t = tid >> 2, e0 = (tid & 3) * 16;
    const float* row = k + (((size_t)b * Tn + t0 + t) * Hn + h) * 64 + e0;
    u16* knr = kn + ((size_t)bh * Tn + t0 + t) * 64 + e0;
    float ss = 0.f;
#pragma unroll
    for (int q4 = 0; q4 < 4; ++q4) {
      float4 vv = *reinterpret_cast<const float4*>(row + q4 * 4);
      float x0 = vv.x * DATA_NORM, x1 = vv.y * DATA_NORM;
      float x2 = vv.z * DATA_NORM, x3 = vv.w * DATA_NORM;
      ss += x0 * x0 + x1 * x1 + x2 * x2 + x3 * x3;
      ushort4 uu = make_ushort4(f2bf(x0), f2bf(x1), f2bf(x2), f2bf(x3));
      *reinterpret_cast<ushort4*>(&xt[t * 72 + e0 + q4 * 4]) = uu;
      *reinterpret_cast<ushort4*>(knr + q4 * 4) = uu;
    }
    ss += __shfl_xor(ss, 1);
    ss += __shfl_xor(ss, 2);
    if ((tid & 3) == 0) diagk[(size_t)bh * Tn + t0 + t] = 0.5f * ss;
  }
  __syncthreads();
  const int lane = tid & 63, wv = tid >> 6;
  const int lj = lane & 15, lg = lane >> 4;
  bf16x8 a0 = ldb(&xt[(wv * 16 + lj) * 72 + lg * 8]);
  bf16x8 a1 = ldb(&xt[(wv * 16 + lj) * 72 + 32 + lg * 8]);
  float mx = -3e38f;
#pragma unroll
  for (int mt = 0; mt < 17; ++mt) {
    const u16* br = &projbf[(mt * 16 + lj) * 64 + lg * 8];
    f32x4 z = {0.f, 0.f, 0.f, 0.f};
    z = mfma16(a0, ldb(br), z);
    z = mfma16(a1, ldb(br + 32), z);
    int m = mt * 16 + lj;
    if (m < Mn)
      mx = fmaxf(mx, fmaxf(fmaxf(z[0], z[1]), fmaxf(z[2], z[3])));
  }
  mx = fmaxf(mx, __shfl_xor(mx, 1));
  mx = fmaxf(mx, __shfl_xor(mx, 2));
  mx = fmaxf(mx, __shfl_xor(mx, 4));
  mx = fmaxf(mx, __shfl_xor(mx, 8));
  mx = fmaxf(mx, __shfl_xor(mx, 16));
  mx = fmaxf(mx, __shfl_xor(mx, 32));
  if (lane == 0) wred[wv] = mx;
  __syncthreads();
  if (tid == 0)
    atomicMaxF(&kmax[bh], fmaxf(fmaxf(wred[0], wred[1]), fmaxf(wred[2], wred[3])));
}

// ---------------- stage_a: KV^T partial = V^T @ phi_k per chunk + z partial ----------------
__global__ __launch_bounds__(512) void stage_a(
    const float* __restrict__ v, const u16* __restrict__ kn,
    const u16* __restrict__ projbf, const float* __restrict__ diagk,
    const float* __restrict__ kmax, u16* __restrict__ kvT,
    float* __restrict__ zp) {
  __shared__ __align__(16) u16 knl[128 * 72];     // 18,432
  __shared__ __align__(16) u16 Vt[64 * 136];      // 17,408  (V^T [d][t])
  __shared__ __align__(16) u16 strip[288 * 40];   // 23,040  (phi_k^T [m][t-strip 32])
  __shared__ float dkl[128];
  const int tid = threadIdx.x, lane = tid & 63, wv = tid >> 6;
  const int lj = lane & 15, lg = lane >> 4;
  const int c = blockIdx.x & 31, bh = blockIdx.x >> 5;
  const int b = bh / Hn, h = bh % Hn;
  const int t0 = c * CH;
  const float kmx = kmax[bh];

#pragma unroll
  for (int l = 0; l < 2; ++l) {   // kn tile -> LDS
    int idx = tid + l * 512;
    int t = idx >> 3, e8 = (idx & 7) * 8;
    *reinterpret_cast<uint4*>(&knl[t * 72 + e8]) =
        *reinterpret_cast<const uint4*>(&kn[((size_t)bh * Tn + t0 + t) * 64 + e8]);
  }
#pragma unroll
  for (int l = 0; l < 4; ++l) {   // V -> V^T LDS bf16
    int idx = tid + l * 512;
    int t = idx >> 4, d4 = (idx & 15) * 4;
    float4 vv = *reinterpret_cast<const float4*>(
        &v[(((size_t)b * Tn + t0 + t) * Hn + h) * 64 + d4]);
    Vt[(d4 + 0) * 136 + t] = f2bf(vv.x);
    Vt[(d4 + 1) * 136 + t] = f2bf(vv.y);
    Vt[(d4 + 2) * 136 + t] = f2bf(vv.z);
    Vt[(d4 + 3) * 136 + t] = f2bf(vv.w);
  }
  if (tid < 128) dkl[tid] = diagk[(size_t)bh * Tn + t0 + tid];

  float zacc = 0.f;
  f32x4 kvacc[9];
#pragma unroll
  for (int i = 0; i < 9; ++i) kvacc[i] = (f32x4){0.f, 0.f, 0.f, 0.f};
  const int dtile = wv & 3, mg = wv >> 2;
  __syncthreads();

  for (int s = 0; s < 4; ++s) {
    if (s) __syncthreads();
    // P1: dd^T tiles (row=m, col=t), exp -> strip
#pragma unroll
    for (int i = 0; i < 5; ++i) {
      int idx = wv + 8 * i;
      if (idx < 36) {
        int mt = idx % 18, th = idx / 18;
        const u16* ar = &projbf[(mt * 16 + lj) * 64 + lg * 8];
        int trow = s * 32 + th * 16 + lj;
        const u16* br = &knl[trow * 72 + lg * 8];
        f32x4 z = {0.f, 0.f, 0.f, 0.f};
        z = mfma16(ldb(ar), ldb(br), z);
        z = mfma16(ldb(ar + 32), ldb(br + 32), z);
        float dgk = dkl[trow];
#pragma unroll
        for (int r = 0; r < 4; ++r) {
          int m = mt * 16 + lg * 4 + r;
          float val = (m < Mn) ? RATIO * (__expf(z[r] - dgk - kmx) + SM_EPS) : 0.f;
          strip[m * 40 + th * 16 + lj] = f2bf(val);
        }
      }
    }
    __syncthreads();
    // z partial (column sums over t of phi_k = row sums of strip)
    if (tid < MP) {
      const u16* srow = &strip[tid * 40];
#pragma unroll
      for (int o = 0; o < 32; o += 8) {
        bf16x8 vv = ldb(srow + o);
#pragma unroll
        for (int e = 0; e < 8; ++e) zacc += bf2f((u16)vv[e]);
      }
    }
    // KV^T mfma: A = V^T (row d, k=t), B = strip (col m, k=t)
    {
      bf16x8 av = ldb(&Vt[(dtile * 16 + lj) * 136 + s * 32 + lg * 8]);
#pragma unroll
      for (int i = 0; i < 9; ++i) {
        int mt = mg * 9 + i;
        kvacc[i] = mfma16(av, ldb(&strip[(mt * 16 + lj) * 40 + lg * 8]), kvacc[i]);
      }
    }
  }
  // write KV^T partial (row=d, col=m)
  size_t base = ((size_t)(bh * NC + c) * 64) * MP;
#pragma unroll
  for (int i = 0; i < 9; ++i) {
    int mt = mg * 9 + i;
#pragma unroll
    for (int r = 0; r < 4; ++r) {
      int d = dtile * 16 + lg * 4 + r;
      int m = mt * 16 + lj;
      kvT[base + (size_t)d * MP + m] = f2bf(kvacc[i][r]);
    }
  }
  if (tid < MP) zp[((size_t)bh * NC + c) * MP + tid] = zacc;
}

// ---------------- exclusive prefix scans over chunks ----------------
__global__ void scan_kv(u16* __restrict__ kvT) {
  int idx = blockIdx.x * 256 + threadIdx.x;          // 48*64*288
  if (idx >= BH * 64 * MP) return;
  int m = idx % MP;
  int r = idx / MP;
  int d = r % 64, bh = r / 64;
  u16* p = kvT + ((size_t)(bh * NC) * 64 + d) * MP + m;
  const size_t cs = (size_t)64 * MP;
  float acc = 0.f;
  for (int c = 0; c < NC; ++c) {
    float x = bf2f(p[c * cs]);
    p[c * cs] = f2bf(acc);
    acc += x;
  }
}

__global__ void scan_z(float* __restrict__ zp) {
  int idx = blockIdx.x * 256 + threadIdx.x;          // 48*288
  if (idx >= BH * MP) return;
  int m = idx % MP, bh = idx / MP;
  float* p = zp + (size_t)bh * NC * MP + m;
  float acc = 0.f;
  for (int c = 0; c < NC; ++c) {
    float x = p[(size_t)c * MP];
    p[(size_t)c * MP] = acc;
    acc += x;
  }
}

// ---------------- stage_c v3: quarter-strip phi_k + register prefetch ----------------
// A = mask(QK^T); out = (A@V + Q@S_prev) / (rowsum(A) + q.z_prev + eps)
__global__ __launch_bounds__(512, 4) void stage_c(
    const float* __restrict__ v, const u16* __restrict__ kn,
    const u16* __restrict__ projbf, const float* __restrict__ diagk,
    const float* __restrict__ kmax, const u16* __restrict__ phiq,
    const u16* __restrict__ kvT, const float* __restrict__ zp,
    float* __restrict__ out) {
  __shared__ __align__(16) u16 Albuf[128 * 136];          // 34,816
  __shared__ __align__(16) u16 arena[32 * 296 + 32 * 72]; // 23,552 (phik_q + knq; Vt later)
  __shared__ float zl[MP];
  __shared__ float dkl[128];
  __shared__ float rs2[128 * 8];
  __shared__ float qzb[128];
  __shared__ float den[128];

  u16* phik_q = arena;              // [32][296]
  u16* knq    = arena + 32 * 296;   // [32][72]

  const int tid = threadIdx.x, lane = tid & 63, wv = tid >> 6;
  const int lj = lane & 15, lg = lane >> 4;
  const int c = blockIdx.x & 31, bh = blockIdx.x >> 5;
  const int b = bh / Hn, h = bh % Hn;
  const int t0 = c * CH;
  const float kmx = kmax[bh];
  const size_t qbase = ((size_t)bh * Tn + t0) * MP;

  if (tid < MP) zl[tid] = zp[((size_t)bh * NC + c) * MP + tid];
  if (tid < 128) dkl[tid] = diagk[(size_t)bh * Tn + t0 + tid];
#pragma unroll
  for (int l = 0; l < 5; ++l) {   // zero Albuf (2176 uint4)
    int idx = tid + l * 512;
    if (idx < 2176)
      *reinterpret_cast<uint4*>(&Albuf[idx * 8]) = make_uint4(0, 0, 0, 0);
  }
  for (int idx = tid; idx < 128 * 8; idx += 512) rs2[idx] = 0.f;

  for (int qq = 0; qq < 4; ++qq) {
    const int beg = qOFF[qq], end = qOFF[qq + 1];
    const int ia = beg + wv, ib = beg + wv + 8;
    const bool ha = ia < end, hb = ib < end;
    const int tta = ha ? qTT[ia] : 0, tpa = ha ? qTP[ia] : 0;
    const int ttb = hb ? qTT[ib] : 0, tpb = hb ? qTP[ib] : 0;

    // R4: prefetch A-fragments (phiq) for both tiles; lands under kn-load + P1.
    bf16x8 aA[9], aB[9];
    if (ha) {
#pragma unroll
      for (int ks = 0; ks < 9; ++ks)
        aA[ks] = ldb(&phiq[qbase + (size_t)(tta * 16 + lj) * MP + ks * 32 + lg * 8]);
    }
    if (hb) {
#pragma unroll
      for (int ks = 0; ks < 9; ++ks)
        aB[ks] = ldb(&phiq[qbase + (size_t)(ttb * 16 + lj) * MP + ks * 32 + lg * 8]);
    }

    // load kn rows for this quarter (32 rows x 64 e)
    if (tid < 256) {
      int t = tid >> 3, e8 = (tid & 7) * 8;
      *reinterpret_cast<uint4*>(&knq[t * 72 + e8]) =
          *reinterpret_cast<const uint4*>(
              &kn[((size_t)bh * Tn + t0 + qq * 32 + t) * 64 + e8]);
    }
    __syncthreads();

    // P1: phi_k for quarter -> phik_q [32][296]; 36 units (2 t-tiles x 18 m-tiles)
    for (int u = wv; u < 36; u += 8) {
      int t2 = u / 18, mt = u % 18;
      bf16x8 a0 = ldb(&knq[(t2 * 16 + lj) * 72 + lg * 8]);
      bf16x8 a1 = ldb(&knq[(t2 * 16 + lj) * 72 + 32 + lg * 8]);
      const u16* br = &projbf[(mt * 16 + lj) * 64 + lg * 8];
      f32x4 z = {0.f, 0.f, 0.f, 0.f};
      z = mfma16(a0, ldb(br), z);
      z = mfma16(a1, ldb(br + 32), z);
      int m = mt * 16 + lj;
      int tq = t2 * 16 + lg * 4;
#pragma unroll
      for (int r = 0; r < 4; ++r) {
        float val = (m < Mn)
            ? RATIO * (__expf(z[r] - dkl[qq * 32 + tq + r] - kmx) + SM_EPS) : 0.f;
        phik_q[(tq + r) * 296 + m] = f2bf(val);
      }
    }
    __syncthreads();

    // P2: causal QK^T tiles, A from registers, B from LDS
    f32x4 accA = {0.f, 0.f, 0.f, 0.f}, accB = {0.f, 0.f, 0.f, 0.f};
    if (ha) {
#pragma unroll
      for (int ks = 0; ks < 9; ++ks) {
        int m0 = ks * 32;
        accA = mfma16(aA[ks],
                      ldb(&phik_q[((tpa & 1) * 16 + lj) * 296 + m0 + lg * 8]), accA);
        if (hb)
          accB = mfma16(aB[ks],
                        ldb(&phik_q[((tpb & 1) * 16 + lj) * 296 + m0 + lg * 8]), accB);
      }
      // finalize: mask, rowsum, store
#pragma unroll
      for (int pick = 0; pick < 2; ++pick) {
        if (pick == 1 && !hb) break;
        int tt = pick ? ttb : tta, tp = pick ? tpb : tpa;
        f32x4 a = pick ? accB : accA;
        if (tt == tp) {
#pragma unroll
          for (int r = 0; r < 4; ++r)
            if (lj > lg * 4 + r) a[r] = 0.f;
        }
        f32x4 s = a;
#pragma unroll
        for (int r = 0; r < 4; ++r) {
          s[r] += __shfl_xor(s[r], 1);
          s[r] += __shfl_xor(s[r], 2);
          s[r] += __shfl_xor(s[r], 4);
          s[r] += __shfl_xor(s[r], 8);
        }
        if (lj == 0) {
#pragma unroll
          for (int r = 0; r < 4; ++r) rs2[(tt * 16 + lg * 4 + r) * 8 + tp] = s[r];
        }
#pragma unroll
        for (int r = 0; r < 4; ++r)
          Albuf[(tt * 16 + lg * 4 + r) * 136 + tp * 16 + lj] = f2bf(a[r]);
      }
    }
    __syncthreads();
  }

  // stage V^T [64][136] into arena (phik_q/knq dead)
  u16* Vt = arena;
#pragma unroll
  for (int l = 0; l < 4; ++l) {
    int idx = tid + l * 512;
    int t = idx >> 4, d4 = (idx & 15) * 4;
    float4 vv = *reinterpret_cast<const float4*>(
        &v[(((size_t)b * Tn + t0 + t) * Hn + h) * 64 + d4]);
    Vt[(d4 + 0) * 136 + t] = f2bf(vv.x);
    Vt[(d4 + 1) * 136 + t] = f2bf(vv.y);
    Vt[(d4 + 2) * 136 + t] = f2bf(vv.z);
    Vt[(d4 + 3) * 136 + t] = f2bf(vv.w);
  }

  // R4: prefetch P4 operands before the barrier; they land during P3 (LDS-only).
  const size_t kvbase = ((size_t)(bh * NC + c) * 64) * MP;
  bf16x8 qa[9];
#pragma unroll
  for (int ks = 0; ks < 9; ++ks)
    qa[ks] = ldb(&phiq[qbase + (size_t)(wv * 16 + lj) * MP + ks * 32 + lg * 8]);
  bf16x8 kbA[4], kbB[4];
#pragma unroll
  for (int dt = 0; dt < 4; ++dt)
    kbA[dt] = ldb(&kvT[kvbase + (size_t)(dt * 16 + lj) * MP + lg * 8]);
  __syncthreads();

  // P3: O += A @ V (triangular k-step skip)
  f32x4 oacc[4];
#pragma unroll
  for (int dt = 0; dt < 4; ++dt) oacc[dt] = (f32x4){0.f, 0.f, 0.f, 0.f};
  const int ksteps = (wv >> 1) + 1;
  for (int ks = 0; ks < ksteps; ++ks) {
    bf16x8 af = ldb(&Albuf[(wv * 16 + lj) * 136 + ks * 32 + lg * 8]);
#pragma unroll
    for (int dt = 0; dt < 4; ++dt) {
      bf16x8 bf = ldb(&Vt[(dt * 16 + lj) * 136 + ks * 32 + lg * 8]);
      oacc[dt] = mfma16(af, bf, oacc[dt]);
    }
  }

  // P4: O += phi_q @ S_prev; A from regs, B double-buffered in regs; fused qz
  float qz = 0.f;
#pragma unroll
  for (int ks = 0; ks < 9; ++ks) {
    const bf16x8* cur = (ks & 1) ? kbB : kbA;
    bf16x8* nxt = (ks & 1) ? kbA : kbB;
    if (ks < 8) {
      int m1 = (ks + 1) * 32;
#pragma unroll
      for (int dt = 0; dt < 4; ++dt)
        nxt[dt] = ldb(&kvT[kvbase + (size_t)(dt * 16 + lj) * MP + m1 + lg * 8]);
    }
#pragma unroll
    for (int e = 0; e < 8; ++e)
      qz += bf2f((u16)qa[ks][e]) * zl[ks * 32 + lg * 8 + e];
#pragma unroll
    for (int dt = 0; dt < 4; ++dt)
      oacc[dt] = mfma16(qa[ks], cur[dt], oacc[dt]);
  }
  qz += __shfl_xor(qz, 16);
  qz += __shfl_xor(qz, 32);
  if (lane < 16) qzb[wv * 16 + lane] = qz;
  __syncthreads();

  if (tid < 128) {
    float s = qzb[tid] + N_EPS;
#pragma unroll
    for (int t2 = 0; t2 < 8; ++t2) s += rs2[tid * 8 + t2];
    den[tid] = s;
  }
  __syncthreads();

#pragma unroll
  for (int dt = 0; dt < 4; ++dt) {
#pragma unroll
    for (int r = 0; r < 4; ++r) {
      int tl = wv * 16 + lg * 4 + r;
      float o = oacc[dt][r] / den[tl];
      out[(((size_t)b * Tn + t0 + tl) * Hn + h) * 64 + dt * 16 + lj] = o;
    }
  }
}

extern "C" void kernel_launch(void* const* d_in, const int* in_sizes, int n_in,
                              void* d_out, int out_size, void* d_ws, size_t ws_size,
                              hipStream_t stream) {
  const float* q = (const float*)d_in[0];
  const float* k = (const float*)d_in[1];
  const float* v = (const float*)d_in[2];
  const float* proj = (const float*)d_in[3];
  float* out = (float*)d_out;

  char* ws = (char*)d_ws;
  const size_t phiq_b = (size_t)BH * Tn * MP * 2;        // 113,246,208
  const size_t kvT_b  = (size_t)BH * NC * 64 * MP * 2;   //  56,623,104
  const size_t kn_b   = (size_t)BH * Tn * 64 * 2;        //  25,165,824
  const size_t zp_b   = (size_t)BH * NC * MP * 4;        //   1,769,472
  const size_t dk_b   = (size_t)BH * Tn * 4;             //     786,432
  const size_t pj_b   = (size_t)MP * 64 * 2;             //      36,864

  u16*   phiq  = (u16*)ws;
  u16*   kvT   = (u16*)(ws + phiq_b);
  u16*   kn    = (u16*)(ws + phiq_b + kvT_b);
  float* zp    = (float*)(ws + phiq_b + kvT_b + kn_b);
  float* diagk = (float*)(ws + phiq_b + kvT_b + kn_b + zp_b);
  u16*   projbf= (u16*)(ws + phiq_b + kvT_b + kn_b + zp_b + dk_b);
  float* kmax  = (float*)(ws + phiq_b + kvT_b + kn_b + zp_b + dk_b + pj_b);

  prep<<<72, 256, 0, stream>>>(proj, projbf, kmax);
  feat_k<<<BH * 64, 256, 0, stream>>>(k, projbf, kn, diagk, kmax);
  feat_q<<<BH * 64, 256, 0, stream>>>(q, projbf, phiq);
  stage_a<<<BH * NC, 512, 0, stream>>>(v, kn, projbf, diagk, kmax, kvT, zp);
  scan_kv<<<(BH * 64 * MP) / 256, 256, 0, stream>>>(kvT);
  scan_z<<<(BH * MP + 255) / 256, 256, 0, stream>>>(zp);
  stage_c<<<BH * NC, 512, 0, stream>>>(v, kn, projbf, diagk, kmax, phiq, kvT, zp, out);
}